// Round 1
// baseline (96.845 us; speedup 1.0000x reference)
//
#include <hip/hip_runtime.h>
#include <cmath>

#define HH   93
#define WWID 44
#define HWSZ 4092
#define NMAX 24
#define HID  128
#define LATD 1024
#define NB   8

__device__ __forceinline__ float gelu_f(float x) {
  return 0.5f * x * (1.0f + erff(x * 0.70710678118654752440f));
}

// case3 of source row (r + kr - 1) as function of (case5 of r, kr); -1 = out of range
__device__ __constant__ int c_map[5][3] = {{-1,0,1},{0,1,1},{1,1,1},{1,1,2},{1,2,-1}};

// ---------------- K1: latent_cond, tap-sums, f1(9), GroupNorm, f2(9), cbase ----------
__global__ __launch_bounds__(128) void k_pre1(
    const float* __restrict__ latent, const float* __restrict__ Wl, const float* __restrict__ bl,
    const float* __restrict__ Wt, const float* __restrict__ bt,
    const float* __restrict__ g1p, const float* __restrict__ b1g,
    const float* __restrict__ W1, const float* __restrict__ b1p,
    float* __restrict__ f2o, float* __restrict__ cbo)
{
  const int b = blockIdx.x, t = threadIdx.x;
  __shared__ float lc_s[HID];
  const float* lat = latent + b * LATD;
  float a0 = 0.f, a1 = 0.f, a2 = 0.f, a3 = 0.f;
  for (int l = 0; l < LATD; l += 4) {
    a0 = fmaf(lat[l+0], Wl[(l+0)*HID + t], a0);
    a1 = fmaf(lat[l+1], Wl[(l+1)*HID + t], a1);
    a2 = fmaf(lat[l+2], Wl[(l+2)*HID + t], a2);
    a3 = fmaf(lat[l+3], Wl[(l+3)*HID + t], a3);
  }
  float lc = gelu_f(bl[t] + ((a0 + a1) + (a2 + a3)));
  lc_s[t] = lc;
  __syncthreads();

  // u[kr*3+kc] = sum_i lc[i] * Wt[kr][kc][i][t]
  float u[9];
  #pragma unroll
  for (int k = 0; k < 9; ++k) u[k] = 0.f;
  for (int i = 0; i < HID; ++i) {
    float lv = lc_s[i];
    #pragma unroll
    for (int k = 0; k < 9; ++k) u[k] = fmaf(lv, Wt[(k*HID + i)*HID + t], u[k]);
  }
  // f1 for 9 (rcase3, ccase3) combos. Row-valid kr sets: top={1,2}, mid={0,1,2}, bot={0,1}
  float ur[3][3];
  #pragma unroll
  for (int kc = 0; kc < 3; ++kc) {
    ur[0][kc] = u[3+kc] + u[6+kc];
    ur[1][kc] = u[0+kc] + u[3+kc] + u[6+kc];
    ur[2][kc] = u[0+kc] + u[3+kc];
  }
  float btv = bt[t];
  float f1v[9];
  #pragma unroll
  for (int a = 0; a < 3; ++a) {
    f1v[a*3+0] = btv + ur[a][1] + ur[a][2];
    f1v[a*3+1] = btv + ur[a][0] + ur[a][1] + ur[a][2];
    f1v[a*3+2] = btv + ur[a][0] + ur[a][1];
  }
  // GroupNorm(8): weighted stats over 9 cases; spatial counts {1,H-2,1} x {1,W-2,1}
  const float wr[3] = {1.f, (float)(HH-2), 1.f};
  const float wc[3] = {1.f, (float)(WWID-2), 1.f};
  float s1 = 0.f, s2 = 0.f;
  #pragma unroll
  for (int a = 0; a < 3; ++a)
    #pragma unroll
    for (int c = 0; c < 3; ++c) {
      float w = wr[a] * wc[c];
      float v = f1v[a*3+c];
      s1 += w * v;
      s2 += w * v * v;
    }
  // reduce over 16-thread channel group (16 channels/group, lanes 16-aligned in wave)
  #pragma unroll
  for (int off = 1; off < 16; off <<= 1) {
    s1 += __shfl_xor(s1, off);
    s2 += __shfl_xor(s2, off);
  }
  const float invN = 1.f / (float)(16 * HWSZ);
  float mean = s1 * invN;
  float var  = s2 * invN - mean * mean;
  float sc = rsqrtf(var + 1e-5f) * g1p[t];
  float sh = b1g[t] - mean * sc;
  #pragma unroll
  for (int k = 0; k < 9; ++k)
    f2o[(b*9 + k)*HID + t] = gelu_f(fmaf(f1v[k], sc, sh));

  // cbase = b1 + lc @ W1[128:256]
  float cb = b1p[t];
  for (int i = 0; i < HID; ++i) cb = fmaf(lc_s[i], W1[(HID + i)*HID + t], cb);
  cbo[b*HID + t] = cb;
}

// ---------------- K2: t2[b][tap][combo9][o] = sum_i f2[combo][i] * Wc[tap][i][o] -----
__global__ __launch_bounds__(128) void k_pre2(
    const float* __restrict__ f2i, const float* __restrict__ Wc, float* __restrict__ t2o)
{
  const int b = blockIdx.x / 9, tap = blockIdx.x % 9, t = threadIdx.x;
  __shared__ float f2s[9 * HID];
  for (int i = t; i < 9 * HID; i += 128) f2s[i] = f2i[b*9*HID + i];
  __syncthreads();
  float acc[9];
  #pragma unroll
  for (int k = 0; k < 9; ++k) acc[k] = 0.f;
  for (int i = 0; i < HID; ++i) {
    float wv = Wc[(tap*HID + i)*HID + t];
    #pragma unroll
    for (int k = 0; k < 9; ++k) acc[k] = fmaf(f2s[k*HID + i], wv, acc[k]);
  }
  #pragma unroll
  for (int k = 0; k < 9; ++k)
    t2o[((b*9 + tap)*9 + k)*HID + t] = acc[k];
}

// ---------------- K3: f3(25 cases) + logit_case + proj_case -------------------------
__global__ __launch_bounds__(128) void k_pre3(
    const float* __restrict__ t2i, const float* __restrict__ bc,
    const float* __restrict__ Wa, const float* __restrict__ ba,
    const float* __restrict__ W1,
    float* __restrict__ logito, float* __restrict__ projo)
{
  const int bid = blockIdx.x, b = bid / 25, cs = bid % 25;
  const int r5 = cs / 5, c5 = cs % 5, t = threadIdx.x;
  float acc = bc[t];
  #pragma unroll
  for (int kr = 0; kr < 3; ++kr) {
    int rm = c_map[r5][kr];
    if (rm < 0) continue;
    #pragma unroll
    for (int kc = 0; kc < 3; ++kc) {
      int cm = c_map[c5][kc];
      if (cm < 0) continue;
      acc += t2i[((b*9 + kr*3 + kc)*9 + rm*3 + cm)*HID + t];
    }
  }
  float f3v = gelu_f(acc);
  __shared__ float f3s[HID];
  __shared__ float red[2];
  f3s[t] = f3v;
  float part = f3v * Wa[t];
  #pragma unroll
  for (int off = 1; off < 64; off <<= 1) part += __shfl_xor(part, off);
  if ((t & 63) == 0) red[t >> 6] = part;
  __syncthreads();
  if (t == 0) logito[b*32 + cs] = red[0] + red[1] + ba[0];
  // proj_case[h=t] = sum_o f3[o] * W1[o][h]
  float p = 0.f;
  for (int o = 0; o < HID; ++o) p = fmaf(f3s[o], W1[o*HID + t], p);
  projo[(b*25 + cs)*HID + t] = p;
}

// ---------------- K4: per-position attention softmax + MLP -> preds -----------------
__global__ __launch_bounds__(256) void k_pos(
    const int* __restrict__ mask, const int* __restrict__ nbr_idx, const int* __restrict__ nbr_cnt,
    const float* __restrict__ logiti, const float* __restrict__ proji,
    const float* __restrict__ cbasei, const float* __restrict__ W2, const float* __restrict__ b2,
    float* __restrict__ preds)
{
  const int b = blockIdx.y, tid = threadIdx.x;
  __shared__ float4 proj_s[25 * 32];
  __shared__ float4 cbase_s[32];
  __shared__ float  logit_s[32];
  __shared__ float  w2_s[2 * HID];
  const float4* pj = (const float4*)(proji + b*25*HID);
  for (int i = tid; i < 25*32; i += 256) proj_s[i] = pj[i];
  if (tid < 32) cbase_s[tid] = ((const float4*)(cbasei + b*HID))[tid];
  if (tid < 32) logit_s[tid] = (tid < 25) ? logiti[b*32 + tid] : 0.f;
  if (tid < 2*HID) w2_s[tid] = W2[tid];
  __syncthreads();

  const int p = blockIdx.x * 128 + (tid >> 1);
  const int half = tid & 1;
  if (p >= HWSZ) return;

  const int cnt = nbr_cnt[p];
  float ev[NMAX];
  int   cid[NMAX];
  #pragma unroll
  for (int n = 0; n < NMAX; ++n) {
    int q = nbr_idx[p*NMAX + n];
    int qr = q / WWID, qc = q % WWID;
    int r5 = (qr == 0) ? 0 : (qr == 1) ? 1 : (qr == HH-2) ? 3 : (qr == HH-1) ? 4 : 2;
    int c5 = (qc == 0) ? 0 : (qc == 1) ? 1 : (qc == WWID-2) ? 3 : (qc == WWID-1) ? 4 : 2;
    int cd = r5*5 + c5;
    cid[n] = cd;
    bool ok = (n < cnt) && (mask[b*HWSZ + q] == 0);
    ev[n] = ok ? logit_s[cd] : -10000.0f;
  }
  float mx = ev[0];
  #pragma unroll
  for (int n = 1; n < NMAX; ++n) mx = fmaxf(mx, ev[n]);
  float s = 0.f;
  #pragma unroll
  for (int n = 0; n < NMAX; ++n) { ev[n] = expf(ev[n] - mx); s += ev[n]; }
  const float inv = 1.f / s;

  float pr0 = 0.f, pr1 = 0.f;
  const int hb = half * 16;
  #pragma unroll 4
  for (int hq = 0; hq < 16; ++hq) {
    float4 a = make_float4(0.f, 0.f, 0.f, 0.f);
    #pragma unroll
    for (int n = 0; n < NMAX; ++n) {
      float4 pv = proj_s[cid[n]*32 + hb + hq];
      float w = ev[n];
      a.x = fmaf(w, pv.x, a.x);
      a.y = fmaf(w, pv.y, a.y);
      a.z = fmaf(w, pv.z, a.z);
      a.w = fmaf(w, pv.w, a.w);
    }
    float4 cb = cbase_s[hb + hq];
    int h0 = (hb + hq) * 4;
    float g0 = gelu_f(fmaf(inv, a.x, cb.x));
    float g1v = gelu_f(fmaf(inv, a.y, cb.y));
    float g2 = gelu_f(fmaf(inv, a.z, cb.z));
    float g3 = gelu_f(fmaf(inv, a.w, cb.w));
    pr0 = fmaf(g0, w2_s[(h0+0)*2+0], pr0); pr1 = fmaf(g0, w2_s[(h0+0)*2+1], pr1);
    pr0 = fmaf(g1v, w2_s[(h0+1)*2+0], pr0); pr1 = fmaf(g1v, w2_s[(h0+1)*2+1], pr1);
    pr0 = fmaf(g2, w2_s[(h0+2)*2+0], pr0); pr1 = fmaf(g2, w2_s[(h0+2)*2+1], pr1);
    pr0 = fmaf(g3, w2_s[(h0+3)*2+0], pr0); pr1 = fmaf(g3, w2_s[(h0+3)*2+1], pr1);
  }
  pr0 += __shfl_xor(pr0, 1);
  pr1 += __shfl_xor(pr1, 1);
  if (half == 0) {
    preds[(b*HWSZ + p)*2 + 0] = pr0 + b2[0];
    preds[(b*HWSZ + p)*2 + 1] = pr1 + b2[1];
  }
}

// ---------------- K5: zero outputs, per-batch mask scan, packed scatter -------------
__global__ __launch_bounds__(256) void k_pack(
    const int* __restrict__ mask, const float* __restrict__ preds, float* __restrict__ out)
{
  const int b = blockIdx.x, t = threadIdx.x;
  float* predo = out + b*HWSZ*2;
  float* idxo  = out + NB*HWSZ*2 + b*HWSZ*2;
  float* valo  = out + NB*HWSZ*4 + b*HWSZ;
  for (int i = t; i < HWSZ*2; i += 256) { predo[i] = 0.f; idxo[i] = 0.f; }
  for (int i = t; i < HWSZ; i += 256) valo[i] = 0.f;

  const int base = t * 16;
  int m[16];
  int cnt = 0;
  #pragma unroll
  for (int j = 0; j < 16; ++j) {
    int p = base + j;
    m[j] = (p < HWSZ) ? ((mask[b*HWSZ + p] > 0) ? 1 : 0) : 0;
    cnt += m[j];
  }
  __shared__ int scan_s[256];
  scan_s[t] = cnt;
  __syncthreads();
  for (int off = 1; off < 256; off <<= 1) {
    int v = (t >= off) ? scan_s[t - off] : 0;
    __syncthreads();
    scan_s[t] += v;
    __syncthreads();
  }
  int slot = (t > 0) ? scan_s[t - 1] : 0;
  #pragma unroll
  for (int j = 0; j < 16; ++j) {
    int p = base + j;
    if (p < HWSZ && m[j]) {
      predo[slot*2 + 0] = preds[(b*HWSZ + p)*2 + 0];
      predo[slot*2 + 1] = preds[(b*HWSZ + p)*2 + 1];
      idxo[slot*2 + 0] = (float)(p / WWID);
      idxo[slot*2 + 1] = (float)(p % WWID);
      valo[slot] = 1.0f;
      ++slot;
    }
  }
}

extern "C" void kernel_launch(void* const* d_in, const int* in_sizes, int n_in,
                              void* d_out, int out_size, void* d_ws, size_t ws_size,
                              hipStream_t stream) {
  (void)in_sizes; (void)n_in; (void)out_size; (void)ws_size;
  const float* latent  = (const float*)d_in[1];
  const int*   mask    = (const int*)d_in[2];
  const int*   nbr_idx = (const int*)d_in[3];
  const int*   nbr_cnt = (const int*)d_in[4];
  const float* Wl  = (const float*)d_in[5];
  const float* bl  = (const float*)d_in[6];
  const float* Wt  = (const float*)d_in[7];
  const float* bt  = (const float*)d_in[8];
  const float* g1p = (const float*)d_in[9];
  const float* b1g = (const float*)d_in[10];
  const float* Wc  = (const float*)d_in[11];
  const float* bc  = (const float*)d_in[12];
  const float* Wa  = (const float*)d_in[13];
  const float* ba  = (const float*)d_in[14];
  const float* W1  = (const float*)d_in[15];
  const float* b1p = (const float*)d_in[16];
  const float* W2  = (const float*)d_in[17];
  const float* b2  = (const float*)d_in[18];

  float* ws    = (float*)d_ws;
  float* f2    = ws;               // 8*9*128    = 9216
  float* t2    = ws + 9216;        // 8*9*9*128  = 82944
  float* logit = ws + 92160;       // 8*32       = 256
  float* proj  = ws + 92416;       // 8*25*128   = 25600
  float* cbase = ws + 118016;      // 8*128      = 1024
  float* preds = ws + 119040;      // 8*4092*2   = 65472   (total 184512 floats)

  k_pre1<<<NB, 128, 0, stream>>>(latent, Wl, bl, Wt, bt, g1p, b1g, W1, b1p, f2, cbase);
  k_pre2<<<NB*9, 128, 0, stream>>>(f2, Wc, t2);
  k_pre3<<<NB*25, 128, 0, stream>>>(t2, bc, Wa, ba, W1, logit, proj);
  dim3 g4((HWSZ + 127) / 128, NB);
  k_pos<<<g4, 256, 0, stream>>>(mask, nbr_idx, nbr_cnt, logit, proj, cbase, W2, b2, preds);
  k_pack<<<NB, 256, 0, stream>>>(mask, preds, (float*)d_out);
}

// Round 2
// 77.613 us; speedup vs baseline: 1.2478x; 1.2478x over previous
//
#include <hip/hip_runtime.h>
#include <cmath>

#define HH   93
#define WWID 44
#define HWSZ 4092
#define NMAX 24
#define HID  128
#define LATD 1024
#define NB   8

__device__ __forceinline__ float gelu_f(float x) {
  return 0.5f * x * (1.0f + erff(x * 0.70710678118654752440f));
}

// case3 of source row (r + kr - 1) as function of (case5 of r, kr); -1 = out of range
__device__ __constant__ int c_map[5][3] = {{-1,0,1},{0,1,1},{1,1,1},{1,1,2},{1,2,-1}};

// ---------------- K1a: partial lat@Wl over 128-L chunks ------------------------------
// grid (8 splits, B) x 256 threads; part[(b*8+split)*128+ch]
__global__ __launch_bounds__(256) void k_lc_part(
    const float* __restrict__ latent, const float* __restrict__ Wl, float* __restrict__ part)
{
  const int split = blockIdx.x, b = blockIdx.y, tid = threadIdx.x;
  const int ch = tid & 127, half = tid >> 7;
  const float* lat = latent + b * LATD + split * 128 + half * 64;
  const float* w   = Wl + (split * 128 + half * 64) * HID + ch;
  float a0 = 0.f, a1 = 0.f, a2 = 0.f, a3 = 0.f;
  #pragma unroll 4
  for (int l = 0; l < 64; l += 4) {
    a0 = fmaf(lat[l+0], w[(l+0)*HID], a0);
    a1 = fmaf(lat[l+1], w[(l+1)*HID], a1);
    a2 = fmaf(lat[l+2], w[(l+2)*HID], a2);
    a3 = fmaf(lat[l+3], w[(l+3)*HID], a3);
  }
  __shared__ float red[256];
  red[tid] = ((a0 + a1) + (a2 + a3));
  __syncthreads();
  if (tid < 128) part[(b*8 + split)*HID + ch] = red[tid] + red[tid + 128];
}

// ---------------- K1b: per-tap reduction u[b][tap][ch] -------------------------------
// grid (10, B) x 256 threads. tap<9: Wt tap; tap==9: W1[128:] (cbase half).
// Each block redundantly finalizes lc from the 8 partials (cheap: 8 loads/thread).
__global__ __launch_bounds__(256) void k_tap(
    const float* __restrict__ part, const float* __restrict__ bl,
    const float* __restrict__ Wt, const float* __restrict__ W1,
    float* __restrict__ u)
{
  const int tap = blockIdx.x, b = blockIdx.y, tid = threadIdx.x;
  const int ch = tid & 127, half = tid >> 7;
  __shared__ float lc_s[HID];
  if (tid < 128) {
    float s = bl[tid];
    #pragma unroll
    for (int sp = 0; sp < 8; ++sp) s += part[(b*8 + sp)*HID + tid];
    lc_s[tid] = gelu_f(s);
  }
  __syncthreads();
  const float* w = (tap < 9) ? (Wt + (tap*HID)*HID + ch)
                             : (W1 + HID*HID + ch);
  const int i0 = half * 64;
  float a0 = 0.f, a1 = 0.f, a2 = 0.f, a3 = 0.f;
  #pragma unroll 4
  for (int i = 0; i < 64; i += 4) {
    a0 = fmaf(lc_s[i0+i+0], w[(i0+i+0)*HID], a0);
    a1 = fmaf(lc_s[i0+i+1], w[(i0+i+1)*HID], a1);
    a2 = fmaf(lc_s[i0+i+2], w[(i0+i+2)*HID], a2);
    a3 = fmaf(lc_s[i0+i+3], w[(i0+i+3)*HID], a3);
  }
  __shared__ float red[256];
  red[tid] = ((a0 + a1) + (a2 + a3));
  __syncthreads();
  if (tid < 128) u[(b*10 + tap)*HID + ch] = red[tid] + red[tid + 128];
}

// ---------------- K1c: f1(9), GroupNorm, f2(9), cbase --------------------------------
__global__ __launch_bounds__(128) void k_gn(
    const float* __restrict__ u, const float* __restrict__ bt,
    const float* __restrict__ g1p, const float* __restrict__ b1g,
    const float* __restrict__ b1p,
    float* __restrict__ f2o, float* __restrict__ cbo)
{
  const int b = blockIdx.x, t = threadIdx.x;
  float uv[9];
  #pragma unroll
  for (int k = 0; k < 9; ++k) uv[k] = u[(b*10 + k)*HID + t];
  // f1 for 9 (rcase3, ccase3) combos. Row-valid kr sets: top={1,2}, mid={0,1,2}, bot={0,1}
  float ur[3][3];
  #pragma unroll
  for (int kc = 0; kc < 3; ++kc) {
    ur[0][kc] = uv[3+kc] + uv[6+kc];
    ur[1][kc] = uv[0+kc] + uv[3+kc] + uv[6+kc];
    ur[2][kc] = uv[0+kc] + uv[3+kc];
  }
  float btv = bt[t];
  float f1v[9];
  #pragma unroll
  for (int a = 0; a < 3; ++a) {
    f1v[a*3+0] = btv + ur[a][1] + ur[a][2];
    f1v[a*3+1] = btv + ur[a][0] + ur[a][1] + ur[a][2];
    f1v[a*3+2] = btv + ur[a][0] + ur[a][1];
  }
  // GroupNorm(8): weighted stats over 9 cases; spatial counts {1,H-2,1} x {1,W-2,1}
  const float wr[3] = {1.f, (float)(HH-2), 1.f};
  const float wc[3] = {1.f, (float)(WWID-2), 1.f};
  float s1 = 0.f, s2 = 0.f;
  #pragma unroll
  for (int a = 0; a < 3; ++a)
    #pragma unroll
    for (int c = 0; c < 3; ++c) {
      float w = wr[a] * wc[c];
      float v = f1v[a*3+c];
      s1 += w * v;
      s2 += w * v * v;
    }
  #pragma unroll
  for (int off = 1; off < 16; off <<= 1) {
    s1 += __shfl_xor(s1, off);
    s2 += __shfl_xor(s2, off);
  }
  const float invN = 1.f / (float)(16 * HWSZ);
  float mean = s1 * invN;
  float var  = s2 * invN - mean * mean;
  float sc = rsqrtf(var + 1e-5f) * g1p[t];
  float sh = b1g[t] - mean * sc;
  #pragma unroll
  for (int k = 0; k < 9; ++k)
    f2o[(b*9 + k)*HID + t] = gelu_f(fmaf(f1v[k], sc, sh));
  cbo[b*HID + t] = b1p[t] + u[(b*10 + 9)*HID + t];
}

// ---------------- K2: t2[b][tap][combo9][o] = sum_i f2[combo][i] * Wc[tap][i][o] -----
__global__ __launch_bounds__(128) void k_pre2(
    const float* __restrict__ f2i, const float* __restrict__ Wc, float* __restrict__ t2o)
{
  const int b = blockIdx.x / 9, tap = blockIdx.x % 9, t = threadIdx.x;
  __shared__ float f2s[9 * HID];
  for (int i = t; i < 9 * HID; i += 128) f2s[i] = f2i[b*9*HID + i];
  __syncthreads();
  float acc[9];
  #pragma unroll
  for (int k = 0; k < 9; ++k) acc[k] = 0.f;
  for (int i = 0; i < HID; ++i) {
    float wv = Wc[(tap*HID + i)*HID + t];
    #pragma unroll
    for (int k = 0; k < 9; ++k) acc[k] = fmaf(f2s[k*HID + i], wv, acc[k]);
  }
  #pragma unroll
  for (int k = 0; k < 9; ++k)
    t2o[((b*9 + tap)*9 + k)*HID + t] = acc[k];
}

// ---------------- K3: f3(25 cases) + logit_case + proj_case -------------------------
__global__ __launch_bounds__(128) void k_pre3(
    const float* __restrict__ t2i, const float* __restrict__ bc,
    const float* __restrict__ Wa, const float* __restrict__ ba,
    const float* __restrict__ W1,
    float* __restrict__ logito, float* __restrict__ projo)
{
  const int bid = blockIdx.x, b = bid / 25, cs = bid % 25;
  const int r5 = cs / 5, c5 = cs % 5, t = threadIdx.x;
  float acc = bc[t];
  #pragma unroll
  for (int kr = 0; kr < 3; ++kr) {
    int rm = c_map[r5][kr];
    if (rm < 0) continue;
    #pragma unroll
    for (int kc = 0; kc < 3; ++kc) {
      int cm = c_map[c5][kc];
      if (cm < 0) continue;
      acc += t2i[((b*9 + kr*3 + kc)*9 + rm*3 + cm)*HID + t];
    }
  }
  float f3v = gelu_f(acc);
  __shared__ float f3s[HID];
  __shared__ float red[2];
  f3s[t] = f3v;
  float part = f3v * Wa[t];
  #pragma unroll
  for (int off = 1; off < 64; off <<= 1) part += __shfl_xor(part, off);
  if ((t & 63) == 0) red[t >> 6] = part;
  __syncthreads();
  if (t == 0) logito[b*32 + cs] = red[0] + red[1] + ba[0];
  // proj_case[h=t] = sum_o f3[o] * W1[o][h]
  float p = 0.f;
  for (int o = 0; o < HID; ++o) p = fmaf(f3s[o], W1[o*HID + t], p);
  projo[(b*25 + cs)*HID + t] = p;
}

// ---------------- K4: per-position attention softmax + MLP -> preds -----------------
__global__ __launch_bounds__(256) void k_pos(
    const int* __restrict__ mask, const int* __restrict__ nbr_idx, const int* __restrict__ nbr_cnt,
    const float* __restrict__ logiti, const float* __restrict__ proji,
    const float* __restrict__ cbasei, const float* __restrict__ W2, const float* __restrict__ b2,
    float* __restrict__ preds)
{
  const int b = blockIdx.y, tid = threadIdx.x;
  __shared__ float4 proj_s[25 * 32];
  __shared__ float4 cbase_s[32];
  __shared__ float  logit_s[32];
  __shared__ float  w2_s[2 * HID];
  const float4* pj = (const float4*)(proji + b*25*HID);
  for (int i = tid; i < 25*32; i += 256) proj_s[i] = pj[i];
  if (tid < 32) cbase_s[tid] = ((const float4*)(cbasei + b*HID))[tid];
  if (tid < 32) logit_s[tid] = (tid < 25) ? logiti[b*32 + tid] : 0.f;
  if (tid < 2*HID) w2_s[tid] = W2[tid];
  __syncthreads();

  const int p = blockIdx.x * 128 + (tid >> 1);
  const int half = tid & 1;
  if (p >= HWSZ) return;

  const int cnt = nbr_cnt[p];
  float ev[NMAX];
  int   cid[NMAX];
  #pragma unroll
  for (int n = 0; n < NMAX; ++n) {
    int q = nbr_idx[p*NMAX + n];
    int qr = q / WWID, qc = q % WWID;
    int r5 = (qr == 0) ? 0 : (qr == 1) ? 1 : (qr == HH-2) ? 3 : (qr == HH-1) ? 4 : 2;
    int c5 = (qc == 0) ? 0 : (qc == 1) ? 1 : (qc == WWID-2) ? 3 : (qc == WWID-1) ? 4 : 2;
    int cd = r5*5 + c5;
    cid[n] = cd;
    bool ok = (n < cnt) && (mask[b*HWSZ + q] == 0);
    ev[n] = ok ? logit_s[cd] : -10000.0f;
  }
  float mx = ev[0];
  #pragma unroll
  for (int n = 1; n < NMAX; ++n) mx = fmaxf(mx, ev[n]);
  float s = 0.f;
  #pragma unroll
  for (int n = 0; n < NMAX; ++n) { ev[n] = expf(ev[n] - mx); s += ev[n]; }
  const float inv = 1.f / s;

  float pr0 = 0.f, pr1 = 0.f;
  const int hb = half * 16;
  #pragma unroll 4
  for (int hq = 0; hq < 16; ++hq) {
    float4 a = make_float4(0.f, 0.f, 0.f, 0.f);
    #pragma unroll
    for (int n = 0; n < NMAX; ++n) {
      float4 pv = proj_s[cid[n]*32 + hb + hq];
      float w = ev[n];
      a.x = fmaf(w, pv.x, a.x);
      a.y = fmaf(w, pv.y, a.y);
      a.z = fmaf(w, pv.z, a.z);
      a.w = fmaf(w, pv.w, a.w);
    }
    float4 cb = cbase_s[hb + hq];
    int h0 = (hb + hq) * 4;
    float g0 = gelu_f(fmaf(inv, a.x, cb.x));
    float g1v = gelu_f(fmaf(inv, a.y, cb.y));
    float g2 = gelu_f(fmaf(inv, a.z, cb.z));
    float g3 = gelu_f(fmaf(inv, a.w, cb.w));
    pr0 = fmaf(g0, w2_s[(h0+0)*2+0], pr0); pr1 = fmaf(g0, w2_s[(h0+0)*2+1], pr1);
    pr0 = fmaf(g1v, w2_s[(h0+1)*2+0], pr0); pr1 = fmaf(g1v, w2_s[(h0+1)*2+1], pr1);
    pr0 = fmaf(g2, w2_s[(h0+2)*2+0], pr0); pr1 = fmaf(g2, w2_s[(h0+2)*2+1], pr1);
    pr0 = fmaf(g3, w2_s[(h0+3)*2+0], pr0); pr1 = fmaf(g3, w2_s[(h0+3)*2+1], pr1);
  }
  pr0 += __shfl_xor(pr0, 1);
  pr1 += __shfl_xor(pr1, 1);
  if (half == 0) {
    preds[(b*HWSZ + p)*2 + 0] = pr0 + b2[0];
    preds[(b*HWSZ + p)*2 + 1] = pr1 + b2[1];
  }
}

// ---------------- K5: zero outputs, per-batch mask scan, packed scatter -------------
__global__ __launch_bounds__(256) void k_pack(
    const int* __restrict__ mask, const float* __restrict__ preds, float* __restrict__ out)
{
  const int b = blockIdx.x, t = threadIdx.x;
  float* predo = out + b*HWSZ*2;
  float* idxo  = out + NB*HWSZ*2 + b*HWSZ*2;
  float* valo  = out + NB*HWSZ*4 + b*HWSZ;
  for (int i = t; i < HWSZ*2; i += 256) { predo[i] = 0.f; idxo[i] = 0.f; }
  for (int i = t; i < HWSZ; i += 256) valo[i] = 0.f;

  const int base = t * 16;
  int m[16];
  int cnt = 0;
  #pragma unroll
  for (int j = 0; j < 16; ++j) {
    int p = base + j;
    m[j] = (p < HWSZ) ? ((mask[b*HWSZ + p] > 0) ? 1 : 0) : 0;
    cnt += m[j];
  }
  __shared__ int scan_s[256];
  scan_s[t] = cnt;
  __syncthreads();
  for (int off = 1; off < 256; off <<= 1) {
    int v = (t >= off) ? scan_s[t - off] : 0;
    __syncthreads();
    scan_s[t] += v;
    __syncthreads();
  }
  int slot = (t > 0) ? scan_s[t - 1] : 0;
  #pragma unroll
  for (int j = 0; j < 16; ++j) {
    int p = base + j;
    if (p < HWSZ && m[j]) {
      predo[slot*2 + 0] = preds[(b*HWSZ + p)*2 + 0];
      predo[slot*2 + 1] = preds[(b*HWSZ + p)*2 + 1];
      idxo[slot*2 + 0] = (float)(p / WWID);
      idxo[slot*2 + 1] = (float)(p % WWID);
      valo[slot] = 1.0f;
      ++slot;
    }
  }
}

extern "C" void kernel_launch(void* const* d_in, const int* in_sizes, int n_in,
                              void* d_out, int out_size, void* d_ws, size_t ws_size,
                              hipStream_t stream) {
  (void)in_sizes; (void)n_in; (void)out_size; (void)ws_size;
  const float* latent  = (const float*)d_in[1];
  const int*   mask    = (const int*)d_in[2];
  const int*   nbr_idx = (const int*)d_in[3];
  const int*   nbr_cnt = (const int*)d_in[4];
  const float* Wl  = (const float*)d_in[5];
  const float* bl  = (const float*)d_in[6];
  const float* Wt  = (const float*)d_in[7];
  const float* bt  = (const float*)d_in[8];
  const float* g1p = (const float*)d_in[9];
  const float* b1g = (const float*)d_in[10];
  const float* Wc  = (const float*)d_in[11];
  const float* bc  = (const float*)d_in[12];
  const float* Wa  = (const float*)d_in[13];
  const float* ba  = (const float*)d_in[14];
  const float* W1  = (const float*)d_in[15];
  const float* b1p = (const float*)d_in[16];
  const float* W2  = (const float*)d_in[17];
  const float* b2  = (const float*)d_in[18];

  float* ws    = (float*)d_ws;
  float* f2    = ws;               // 8*9*128    = 9216
  float* t2    = ws + 9216;        // 8*9*9*128  = 82944
  float* logit = ws + 92160;       // 8*32       = 256
  float* proj  = ws + 92416;       // 8*25*128   = 25600
  float* cbase = ws + 118016;      // 8*128      = 1024
  float* preds = ws + 119040;      // 8*4092*2   = 65472   (total 184512 floats)
  // part/u overlay the preds region (preds is dead until k_pos writes it)
  float* part  = preds;            // 8*8*128  = 8192
  float* u     = preds + 8192;     // 8*10*128 = 10240

  dim3 g1a(8, NB);
  k_lc_part<<<g1a, 256, 0, stream>>>(latent, Wl, part);
  dim3 g1b(10, NB);
  k_tap<<<g1b, 256, 0, stream>>>(part, bl, Wt, W1, u);
  k_gn<<<NB, 128, 0, stream>>>(u, bt, g1p, b1g, b1p, f2, cbase);
  k_pre2<<<NB*9, 128, 0, stream>>>(f2, Wc, t2);
  k_pre3<<<NB*25, 128, 0, stream>>>(t2, bc, Wa, ba, W1, logit, proj);
  dim3 g4((HWSZ + 127) / 128, NB);
  k_pos<<<g4, 256, 0, stream>>>(mask, nbr_idx, nbr_cnt, logit, proj, cbase, W2, b2, preds);
  k_pack<<<NB, 256, 0, stream>>>(mask, preds, (float*)d_out);
}

// Round 3
// 57.370 us; speedup vs baseline: 1.6881x; 1.3528x over previous
//
#include <hip/hip_runtime.h>
#include <cmath>

#define HH   93
#define WWID 44
#define HWSZ 4092
#define NMAX 24
#define HID  128
#define LATD 1024
#define NB   8

__device__ __forceinline__ float gelu_f(float x) {
  return 0.5f * x * (1.0f + erff(x * 0.70710678118654752440f));
}

// case3 of source row (r + kr - 1) as function of (case5 of r, kr); -1 = out of range
__device__ __constant__ int c_map[5][3] = {{-1,0,1},{0,1,1},{1,1,1},{1,1,2},{1,2,-1}};

// ---------------- K1a: partial lat@Wl --------------------------------------------------
// grid (8 splits, B) x 256 thr; thread = (h4 = ch-quad, lg = 16-wide L-group)
__global__ __launch_bounds__(256) void k_lc_part(
    const float* __restrict__ latent, const float* __restrict__ Wl, float* __restrict__ part)
{
  const int split = blockIdx.x, b = blockIdx.y, tid = threadIdx.x;
  const int h4 = tid & 31, lg = tid >> 5;
  const int L0 = split * 128 + lg * 16;
  const float* lat = latent + b * LATD;
  const float4* w4 = (const float4*)Wl;
  float4 a = make_float4(0.f, 0.f, 0.f, 0.f);
  #pragma unroll
  for (int i = 0; i < 16; ++i) {
    const int L = L0 + i;
    const float lv = lat[L];
    const float4 wv = w4[L*32 + h4];
    a.x = fmaf(lv, wv.x, a.x); a.y = fmaf(lv, wv.y, a.y);
    a.z = fmaf(lv, wv.z, a.z); a.w = fmaf(lv, wv.w, a.w);
  }
  __shared__ float red[8 * HID];
  ((float4*)red)[lg*32 + h4] = a;
  __syncthreads();
  if (tid < HID) {
    float s = 0.f;
    #pragma unroll
    for (int g = 0; g < 8; ++g) s += red[g*HID + tid];
    part[(b*8 + split)*HID + tid] = s;
  }
}

// ---------------- K1b: per-tap reduction u[b][tap][ch]; tap 9 writes cbase -------------
__global__ __launch_bounds__(256) void k_tap(
    const float* __restrict__ part, const float* __restrict__ bl,
    const float* __restrict__ Wt, const float* __restrict__ W1, const float* __restrict__ b1p,
    float* __restrict__ u, float* __restrict__ cbo)
{
  const int tap = blockIdx.x, b = blockIdx.y, tid = threadIdx.x;
  const int h4 = tid & 31, ig = tid >> 5;
  __shared__ float lc_s[HID];
  __shared__ float red[8 * HID];
  if (tid < HID) {
    float s = bl[tid];
    #pragma unroll
    for (int sp = 0; sp < 8; ++sp) s += part[(b*8 + sp)*HID + tid];
    lc_s[tid] = gelu_f(s);
  }
  __syncthreads();
  const float4* w4 = (tap < 9) ? ((const float4*)(Wt + tap*HID*HID))
                               : ((const float4*)(W1 + HID*HID));
  float4 a = make_float4(0.f, 0.f, 0.f, 0.f);
  #pragma unroll
  for (int i = 0; i < 16; ++i) {
    const int I = ig*16 + i;
    const float lv = lc_s[I];
    const float4 wv = w4[I*32 + h4];
    a.x = fmaf(lv, wv.x, a.x); a.y = fmaf(lv, wv.y, a.y);
    a.z = fmaf(lv, wv.z, a.z); a.w = fmaf(lv, wv.w, a.w);
  }
  ((float4*)red)[ig*32 + h4] = a;
  __syncthreads();
  if (tid < HID) {
    float s = 0.f;
    #pragma unroll
    for (int g = 0; g < 8; ++g) s += red[g*HID + tid];
    if (tap < 9) u[(b*10 + tap)*HID + tid] = s;
    else         cbo[b*HID + tid] = b1p[tid] + s;
  }
}

// ---------------- K2: fused GN + t2[b][tap][combo9][o] ---------------------------------
// grid (9 taps, B) x 256 thr; thread = (o4, ig); fuses old k_gn (recompute f2 per block)
__global__ __launch_bounds__(256) void k_pre2(
    const float* __restrict__ u, const float* __restrict__ bt,
    const float* __restrict__ g1p, const float* __restrict__ b1g,
    const float* __restrict__ Wc, float* __restrict__ t2o)
{
  const int tap = blockIdx.x, b = blockIdx.y, tid = threadIdx.x;
  const int o4 = tid & 31, ig = tid >> 5;
  __shared__ float f2s[9 * HID];
  __shared__ float red[8 * 9 * HID];
  if (tid < HID) {
    const int t = tid;
    float uv[9];
    #pragma unroll
    for (int k = 0; k < 9; ++k) uv[k] = u[(b*10 + k)*HID + t];
    float ur[3][3];
    #pragma unroll
    for (int kc = 0; kc < 3; ++kc) {
      ur[0][kc] = uv[3+kc] + uv[6+kc];
      ur[1][kc] = uv[0+kc] + uv[3+kc] + uv[6+kc];
      ur[2][kc] = uv[0+kc] + uv[3+kc];
    }
    const float btv = bt[t];
    float f1v[9];
    #pragma unroll
    for (int a = 0; a < 3; ++a) {
      f1v[a*3+0] = btv + ur[a][1] + ur[a][2];
      f1v[a*3+1] = btv + ur[a][0] + ur[a][1] + ur[a][2];
      f1v[a*3+2] = btv + ur[a][0] + ur[a][1];
    }
    const float wr[3] = {1.f, (float)(HH-2), 1.f};
    const float wc[3] = {1.f, (float)(WWID-2), 1.f};
    float s1 = 0.f, s2 = 0.f;
    #pragma unroll
    for (int a = 0; a < 3; ++a)
      #pragma unroll
      for (int c = 0; c < 3; ++c) {
        const float w = wr[a] * wc[c];
        const float v = f1v[a*3+c];
        s1 += w * v;
        s2 += w * v * v;
      }
    #pragma unroll
    for (int off = 1; off < 16; off <<= 1) {
      s1 += __shfl_xor(s1, off);
      s2 += __shfl_xor(s2, off);
    }
    const float invN = 1.f / (float)(16 * HWSZ);
    const float mean = s1 * invN;
    const float var  = s2 * invN - mean * mean;
    const float sc = rsqrtf(var + 1e-5f) * g1p[t];
    const float sh = b1g[t] - mean * sc;
    #pragma unroll
    for (int k = 0; k < 9; ++k)
      f2s[k*HID + t] = gelu_f(fmaf(f1v[k], sc, sh));
  }
  __syncthreads();
  const float4* w4 = (const float4*)(Wc + tap*HID*HID);
  float4 acc[9];
  #pragma unroll
  for (int k = 0; k < 9; ++k) acc[k] = make_float4(0.f, 0.f, 0.f, 0.f);
  #pragma unroll
  for (int i = 0; i < 16; ++i) {
    const int I = ig*16 + i;
    const float4 wv = w4[I*32 + o4];
    #pragma unroll
    for (int k = 0; k < 9; ++k) {
      const float f = f2s[k*HID + I];
      acc[k].x = fmaf(f, wv.x, acc[k].x);
      acc[k].y = fmaf(f, wv.y, acc[k].y);
      acc[k].z = fmaf(f, wv.z, acc[k].z);
      acc[k].w = fmaf(f, wv.w, acc[k].w);
    }
  }
  #pragma unroll
  for (int k = 0; k < 9; ++k)
    ((float4*)red)[(ig*9 + k)*32 + o4] = acc[k];
  __syncthreads();
  for (int j = tid; j < 9*HID; j += 256) {
    float s = 0.f;
    #pragma unroll
    for (int g = 0; g < 8; ++g) s += red[g*9*HID + j];
    t2o[(b*9 + tap)*9*HID + j] = s;
  }
}

// ---------------- K3: f3(25 cases) + logit_case + proj_case ---------------------------
__global__ __launch_bounds__(256) void k_pre3(
    const float* __restrict__ t2i, const float* __restrict__ bc,
    const float* __restrict__ Wa, const float* __restrict__ ba,
    const float* __restrict__ W1,
    float* __restrict__ logito, float* __restrict__ projo)
{
  const int bid = blockIdx.x, b = bid / 25, cs = bid % 25;
  const int r5 = cs / 5, c5 = cs % 5, tid = threadIdx.x;
  __shared__ float f3s[HID];
  __shared__ float red2[2];
  __shared__ float redp[8 * HID];
  if (tid < HID) {
    float acc = bc[tid];
    #pragma unroll
    for (int kr = 0; kr < 3; ++kr) {
      const int rm = c_map[r5][kr];
      if (rm < 0) continue;
      #pragma unroll
      for (int kc = 0; kc < 3; ++kc) {
        const int cm = c_map[c5][kc];
        if (cm < 0) continue;
        acc += t2i[((b*9 + kr*3 + kc)*9 + rm*3 + cm)*HID + tid];
      }
    }
    const float f3v = gelu_f(acc);
    f3s[tid] = f3v;
    float pl = f3v * Wa[tid];
    #pragma unroll
    for (int off = 1; off < 64; off <<= 1) pl += __shfl_xor(pl, off);
    if ((tid & 63) == 0) red2[tid >> 6] = pl;
  }
  __syncthreads();
  const int h4 = tid & 31, og = tid >> 5;
  const float4* w4 = (const float4*)W1;
  float4 a = make_float4(0.f, 0.f, 0.f, 0.f);
  #pragma unroll
  for (int i = 0; i < 16; ++i) {
    const int o = og*16 + i;
    const float f = f3s[o];
    const float4 wv = w4[o*32 + h4];
    a.x = fmaf(f, wv.x, a.x); a.y = fmaf(f, wv.y, a.y);
    a.z = fmaf(f, wv.z, a.z); a.w = fmaf(f, wv.w, a.w);
  }
  ((float4*)redp)[og*32 + h4] = a;
  __syncthreads();
  if (tid < HID) {
    float s = 0.f;
    #pragma unroll
    for (int g = 0; g < 8; ++g) s += redp[g*HID + tid];
    projo[(b*25 + cs)*HID + tid] = s;
  }
  if (tid == 0) logito[b*32 + cs] = red2[0] + red2[1] + ba[0];
}

// ---------------- K4: per-position attention softmax + MLP -> preds -------------------
__global__ __launch_bounds__(256) void k_pos(
    const int* __restrict__ mask, const int* __restrict__ nbr_idx, const int* __restrict__ nbr_cnt,
    const float* __restrict__ logiti, const float* __restrict__ proji,
    const float* __restrict__ cbasei, const float* __restrict__ W2, const float* __restrict__ b2,
    float* __restrict__ preds)
{
  const int b = blockIdx.y, tid = threadIdx.x;
  __shared__ float4 proj_s[25 * 32];
  __shared__ float4 cbase_s[32];
  __shared__ float  logit_s[32];
  __shared__ float  w2_s[2 * HID];
  const float4* pj = (const float4*)(proji + b*25*HID);
  for (int i = tid; i < 25*32; i += 256) proj_s[i] = pj[i];
  if (tid < 32) cbase_s[tid] = ((const float4*)(cbasei + b*HID))[tid];
  if (tid < 32) logit_s[tid] = (tid < 25) ? logiti[b*32 + tid] : 0.f;
  if (tid < 2*HID) w2_s[tid] = W2[tid];
  __syncthreads();

  const int p = blockIdx.x * 128 + (tid >> 1);
  const int half = tid & 1;
  if (p >= HWSZ) return;

  const int cnt = nbr_cnt[p];
  float ev[NMAX];
  int   cid[NMAX];
  #pragma unroll
  for (int n = 0; n < NMAX; ++n) {
    int q = nbr_idx[p*NMAX + n];
    int qr = q / WWID, qc = q % WWID;
    int r5 = (qr == 0) ? 0 : (qr == 1) ? 1 : (qr == HH-2) ? 3 : (qr == HH-1) ? 4 : 2;
    int c5 = (qc == 0) ? 0 : (qc == 1) ? 1 : (qc == WWID-2) ? 3 : (qc == WWID-1) ? 4 : 2;
    int cd = r5*5 + c5;
    cid[n] = cd;
    bool ok = (n < cnt) && (mask[b*HWSZ + q] == 0);
    ev[n] = ok ? logit_s[cd] : -10000.0f;
  }
  float mx = ev[0];
  #pragma unroll
  for (int n = 1; n < NMAX; ++n) mx = fmaxf(mx, ev[n]);
  float s = 0.f;
  #pragma unroll
  for (int n = 0; n < NMAX; ++n) { ev[n] = expf(ev[n] - mx); s += ev[n]; }
  const float inv = 1.f / s;

  float pr0 = 0.f, pr1 = 0.f;
  const int hb = half * 16;
  #pragma unroll 4
  for (int hq = 0; hq < 16; ++hq) {
    float4 a = make_float4(0.f, 0.f, 0.f, 0.f);
    #pragma unroll
    for (int n = 0; n < NMAX; ++n) {
      float4 pv = proj_s[cid[n]*32 + hb + hq];
      float w = ev[n];
      a.x = fmaf(w, pv.x, a.x);
      a.y = fmaf(w, pv.y, a.y);
      a.z = fmaf(w, pv.z, a.z);
      a.w = fmaf(w, pv.w, a.w);
    }
    float4 cb = cbase_s[hb + hq];
    int h0 = (hb + hq) * 4;
    float g0 = gelu_f(fmaf(inv, a.x, cb.x));
    float g1v = gelu_f(fmaf(inv, a.y, cb.y));
    float g2 = gelu_f(fmaf(inv, a.z, cb.z));
    float g3 = gelu_f(fmaf(inv, a.w, cb.w));
    pr0 = fmaf(g0, w2_s[(h0+0)*2+0], pr0); pr1 = fmaf(g0, w2_s[(h0+0)*2+1], pr1);
    pr0 = fmaf(g1v, w2_s[(h0+1)*2+0], pr0); pr1 = fmaf(g1v, w2_s[(h0+1)*2+1], pr1);
    pr0 = fmaf(g2, w2_s[(h0+2)*2+0], pr0); pr1 = fmaf(g2, w2_s[(h0+2)*2+1], pr1);
    pr0 = fmaf(g3, w2_s[(h0+3)*2+0], pr0); pr1 = fmaf(g3, w2_s[(h0+3)*2+1], pr1);
  }
  pr0 += __shfl_xor(pr0, 1);
  pr1 += __shfl_xor(pr1, 1);
  if (half == 0) {
    preds[(b*HWSZ + p)*2 + 0] = pr0 + b2[0];
    preds[(b*HWSZ + p)*2 + 1] = pr1 + b2[1];
  }
}

// ---------------- K5: zero outputs, per-batch mask scan, packed scatter ---------------
__global__ __launch_bounds__(256) void k_pack(
    const int* __restrict__ mask, const float* __restrict__ preds, float* __restrict__ out)
{
  const int b = blockIdx.x, t = threadIdx.x;
  float* predo = out + b*HWSZ*2;
  float* idxo  = out + NB*HWSZ*2 + b*HWSZ*2;
  float* valo  = out + NB*HWSZ*4 + b*HWSZ;
  for (int i = t; i < HWSZ*2; i += 256) { predo[i] = 0.f; idxo[i] = 0.f; }
  for (int i = t; i < HWSZ; i += 256) valo[i] = 0.f;

  const int base = t * 16;
  int m[16];
  int cnt = 0;
  #pragma unroll
  for (int j = 0; j < 16; ++j) {
    int p = base + j;
    m[j] = (p < HWSZ) ? ((mask[b*HWSZ + p] > 0) ? 1 : 0) : 0;
    cnt += m[j];
  }
  __shared__ int scan_s[256];
  scan_s[t] = cnt;
  __syncthreads();
  for (int off = 1; off < 256; off <<= 1) {
    int v = (t >= off) ? scan_s[t - off] : 0;
    __syncthreads();
    scan_s[t] += v;
    __syncthreads();
  }
  int slot = (t > 0) ? scan_s[t - 1] : 0;
  #pragma unroll
  for (int j = 0; j < 16; ++j) {
    int p = base + j;
    if (p < HWSZ && m[j]) {
      predo[slot*2 + 0] = preds[(b*HWSZ + p)*2 + 0];
      predo[slot*2 + 1] = preds[(b*HWSZ + p)*2 + 1];
      idxo[slot*2 + 0] = (float)(p / WWID);
      idxo[slot*2 + 1] = (float)(p % WWID);
      valo[slot] = 1.0f;
      ++slot;
    }
  }
}

extern "C" void kernel_launch(void* const* d_in, const int* in_sizes, int n_in,
                              void* d_out, int out_size, void* d_ws, size_t ws_size,
                              hipStream_t stream) {
  (void)in_sizes; (void)n_in; (void)out_size; (void)ws_size;
  const float* latent  = (const float*)d_in[1];
  const int*   mask    = (const int*)d_in[2];
  const int*   nbr_idx = (const int*)d_in[3];
  const int*   nbr_cnt = (const int*)d_in[4];
  const float* Wl  = (const float*)d_in[5];
  const float* bl  = (const float*)d_in[6];
  const float* Wt  = (const float*)d_in[7];
  const float* bt  = (const float*)d_in[8];
  const float* g1p = (const float*)d_in[9];
  const float* b1g = (const float*)d_in[10];
  const float* Wc  = (const float*)d_in[11];
  const float* bc  = (const float*)d_in[12];
  const float* Wa  = (const float*)d_in[13];
  const float* ba  = (const float*)d_in[14];
  const float* W1  = (const float*)d_in[15];
  const float* b1p = (const float*)d_in[16];
  const float* W2  = (const float*)d_in[17];
  const float* b2  = (const float*)d_in[18];

  float* ws    = (float*)d_ws;
  float* f2u   = ws;               // u: 8*10*128 = 10240 (reuse old f2 slot naming)
  float* t2    = ws + 10240;       // 8*9*9*128  = 82944
  float* logit = ws + 93184;       // 8*32       = 256
  float* proj  = ws + 93440;       // 8*25*128   = 25600
  float* cbase = ws + 119040;      // 8*128      = 1024
  float* preds = ws + 120064;      // 8*4092*2   = 65472
  float* part  = ws + 185536;      // 8*8*128    = 8192   (ws is ~268MB; no overlays)

  dim3 gA(8, NB);
  k_lc_part<<<gA, 256, 0, stream>>>(latent, Wl, part);
  dim3 gB(10, NB);
  k_tap<<<gB, 256, 0, stream>>>(part, bl, Wt, W1, b1p, f2u, cbase);
  dim3 gC(9, NB);
  k_pre2<<<gC, 256, 0, stream>>>(f2u, bt, g1p, b1g, Wc, t2);
  k_pre3<<<NB*25, 256, 0, stream>>>(t2, bc, Wa, ba, W1, logit, proj);
  dim3 g4((HWSZ + 127) / 128, NB);
  k_pos<<<g4, 256, 0, stream>>>(mask, nbr_idx, nbr_cnt, logit, proj, cbase, W2, b2, preds);
  k_pack<<<NB, 256, 0, stream>>>(mask, preds, (float*)d_out);
}

// Round 4
// 56.606 us; speedup vs baseline: 1.7109x; 1.0135x over previous
//
#include <hip/hip_runtime.h>
#include <cmath>

#define HH   93
#define WWID 44
#define HWSZ 4092
#define NMAX 24
#define HID  128
#define LATD 1024
#define NB   8

__device__ __forceinline__ float gelu_f(float x) {
  return 0.5f * x * (1.0f + erff(x * 0.70710678118654752440f));
}

// case3 of source row (r + kr - 1) as function of (case5 of r, kr); -1 = out of range
__device__ __constant__ int c_map[5][3] = {{-1,0,1},{0,1,1},{1,1,1},{1,1,2},{1,2,-1}};

// ---------------- K1: fused lc + per-tap reduction u[b][tap][ch]; tap 9 -> cbase ------
// grid (10 taps, B) x 256 thr. Each block redundantly computes lc (L2-resident Wl).
// Also zeroes d_out (nothing reads it until k_pospack, stream-ordered).
__global__ __launch_bounds__(256) void k_tap(
    const float* __restrict__ latent, const float* __restrict__ Wl,
    const float* __restrict__ bl,
    const float* __restrict__ Wt, const float* __restrict__ W1, const float* __restrict__ b1p,
    float* __restrict__ u, float* __restrict__ cbo, float* __restrict__ outz)
{
  const int tap = blockIdx.x, b = blockIdx.y, tid = threadIdx.x;
  const int h4 = tid & 31, ig = tid >> 5;
  __shared__ float lc_s[HID];
  __shared__ float red[8 * HID];

  // zero d_out: 163680 floats = 40920 float4 over 80*256 = 20480 threads
  {
    const int gtid = (b * 10 + tap) * 256 + tid;
    float4* oz = (float4*)outz;
    const float4 z = make_float4(0.f, 0.f, 0.f, 0.f);
    for (int i = gtid; i < (NB*HWSZ*5)/4; i += 20480) oz[i] = z;
  }

  // ---- lc = gelu(bl + lat @ Wl), split-K over 8 ig-groups of 128 L each ----
  {
    const float* lat = latent + b * LATD;
    const float4* w4 = (const float4*)Wl;
    float4 a = make_float4(0.f, 0.f, 0.f, 0.f);
    #pragma unroll 8
    for (int i = 0; i < 128; ++i) {
      const int L = ig * 128 + i;
      const float lv = lat[L];
      const float4 wv = w4[L*32 + h4];
      a.x = fmaf(lv, wv.x, a.x); a.y = fmaf(lv, wv.y, a.y);
      a.z = fmaf(lv, wv.z, a.z); a.w = fmaf(lv, wv.w, a.w);
    }
    ((float4*)red)[ig*32 + h4] = a;
  }
  __syncthreads();
  if (tid < HID) {
    float s = bl[tid];
    #pragma unroll
    for (int g = 0; g < 8; ++g) s += red[g*HID + tid];
    lc_s[tid] = gelu_f(s);
  }
  __syncthreads();

  // ---- tap reduction: u[tap] = lc @ Wt[tap]  (tap 9: lc @ W1[128:]) ----
  const float4* w4 = (tap < 9) ? ((const float4*)(Wt + tap*HID*HID))
                               : ((const float4*)(W1 + HID*HID));
  float4 a = make_float4(0.f, 0.f, 0.f, 0.f);
  #pragma unroll
  for (int i = 0; i < 16; ++i) {
    const int I = ig*16 + i;
    const float lv = lc_s[I];
    const float4 wv = w4[I*32 + h4];
    a.x = fmaf(lv, wv.x, a.x); a.y = fmaf(lv, wv.y, a.y);
    a.z = fmaf(lv, wv.z, a.z); a.w = fmaf(lv, wv.w, a.w);
  }
  __syncthreads();
  ((float4*)red)[ig*32 + h4] = a;
  __syncthreads();
  if (tid < HID) {
    float s = 0.f;
    #pragma unroll
    for (int g = 0; g < 8; ++g) s += red[g*HID + tid];
    if (tap < 9) u[(b*10 + tap)*HID + tid] = s;
    else         cbo[b*HID + tid] = b1p[tid] + s;
  }
}

// ---------------- K2: fused GN + t2[b][tap][combo9][o] ---------------------------------
__global__ __launch_bounds__(256) void k_pre2(
    const float* __restrict__ u, const float* __restrict__ bt,
    const float* __restrict__ g1p, const float* __restrict__ b1g,
    const float* __restrict__ Wc, float* __restrict__ t2o)
{
  const int tap = blockIdx.x, b = blockIdx.y, tid = threadIdx.x;
  const int o4 = tid & 31, ig = tid >> 5;
  __shared__ float f2s[9 * HID];
  __shared__ float red[8 * 9 * HID];
  if (tid < HID) {
    const int t = tid;
    float uv[9];
    #pragma unroll
    for (int k = 0; k < 9; ++k) uv[k] = u[(b*10 + k)*HID + t];
    float ur[3][3];
    #pragma unroll
    for (int kc = 0; kc < 3; ++kc) {
      ur[0][kc] = uv[3+kc] + uv[6+kc];
      ur[1][kc] = uv[0+kc] + uv[3+kc] + uv[6+kc];
      ur[2][kc] = uv[0+kc] + uv[3+kc];
    }
    const float btv = bt[t];
    float f1v[9];
    #pragma unroll
    for (int a = 0; a < 3; ++a) {
      f1v[a*3+0] = btv + ur[a][1] + ur[a][2];
      f1v[a*3+1] = btv + ur[a][0] + ur[a][1] + ur[a][2];
      f1v[a*3+2] = btv + ur[a][0] + ur[a][1];
    }
    const float wr[3] = {1.f, (float)(HH-2), 1.f};
    const float wc[3] = {1.f, (float)(WWID-2), 1.f};
    float s1 = 0.f, s2 = 0.f;
    #pragma unroll
    for (int a = 0; a < 3; ++a)
      #pragma unroll
      for (int c = 0; c < 3; ++c) {
        const float w = wr[a] * wc[c];
        const float v = f1v[a*3+c];
        s1 += w * v;
        s2 += w * v * v;
      }
    #pragma unroll
    for (int off = 1; off < 16; off <<= 1) {
      s1 += __shfl_xor(s1, off);
      s2 += __shfl_xor(s2, off);
    }
    const float invN = 1.f / (float)(16 * HWSZ);
    const float mean = s1 * invN;
    const float var  = s2 * invN - mean * mean;
    const float sc = rsqrtf(var + 1e-5f) * g1p[t];
    const float sh = b1g[t] - mean * sc;
    #pragma unroll
    for (int k = 0; k < 9; ++k)
      f2s[k*HID + t] = gelu_f(fmaf(f1v[k], sc, sh));
  }
  __syncthreads();
  const float4* w4 = (const float4*)(Wc + tap*HID*HID);
  float4 acc[9];
  #pragma unroll
  for (int k = 0; k < 9; ++k) acc[k] = make_float4(0.f, 0.f, 0.f, 0.f);
  #pragma unroll
  for (int i = 0; i < 16; ++i) {
    const int I = ig*16 + i;
    const float4 wv = w4[I*32 + o4];
    #pragma unroll
    for (int k = 0; k < 9; ++k) {
      const float f = f2s[k*HID + I];
      acc[k].x = fmaf(f, wv.x, acc[k].x);
      acc[k].y = fmaf(f, wv.y, acc[k].y);
      acc[k].z = fmaf(f, wv.z, acc[k].z);
      acc[k].w = fmaf(f, wv.w, acc[k].w);
    }
  }
  #pragma unroll
  for (int k = 0; k < 9; ++k)
    ((float4*)red)[(ig*9 + k)*32 + o4] = acc[k];
  __syncthreads();
  for (int j = tid; j < 9*HID; j += 256) {
    float s = 0.f;
    #pragma unroll
    for (int g = 0; g < 8; ++g) s += red[g*9*HID + j];
    t2o[(b*9 + tap)*9*HID + j] = s;
  }
}

// ---------------- K3: f3(25 cases) + logit_case + proj_case ---------------------------
__global__ __launch_bounds__(256) void k_pre3(
    const float* __restrict__ t2i, const float* __restrict__ bc,
    const float* __restrict__ Wa, const float* __restrict__ ba,
    const float* __restrict__ W1,
    float* __restrict__ logito, float* __restrict__ projo)
{
  const int bid = blockIdx.x, b = bid / 25, cs = bid % 25;
  const int r5 = cs / 5, c5 = cs % 5, tid = threadIdx.x;
  __shared__ float f3s[HID];
  __shared__ float red2[2];
  __shared__ float redp[8 * HID];
  if (tid < HID) {
    float acc = bc[tid];
    #pragma unroll
    for (int kr = 0; kr < 3; ++kr) {
      const int rm = c_map[r5][kr];
      if (rm < 0) continue;
      #pragma unroll
      for (int kc = 0; kc < 3; ++kc) {
        const int cm = c_map[c5][kc];
        if (cm < 0) continue;
        acc += t2i[((b*9 + kr*3 + kc)*9 + rm*3 + cm)*HID + tid];
      }
    }
    const float f3v = gelu_f(acc);
    f3s[tid] = f3v;
    float pl = f3v * Wa[tid];
    #pragma unroll
    for (int off = 1; off < 64; off <<= 1) pl += __shfl_xor(pl, off);
    if ((tid & 63) == 0) red2[tid >> 6] = pl;
  }
  __syncthreads();
  const int h4 = tid & 31, og = tid >> 5;
  const float4* w4 = (const float4*)W1;
  float4 a = make_float4(0.f, 0.f, 0.f, 0.f);
  #pragma unroll
  for (int i = 0; i < 16; ++i) {
    const int o = og*16 + i;
    const float f = f3s[o];
    const float4 wv = w4[o*32 + h4];
    a.x = fmaf(f, wv.x, a.x); a.y = fmaf(f, wv.y, a.y);
    a.z = fmaf(f, wv.z, a.z); a.w = fmaf(f, wv.w, a.w);
  }
  ((float4*)redp)[og*32 + h4] = a;
  __syncthreads();
  if (tid < HID) {
    float s = 0.f;
    #pragma unroll
    for (int g = 0; g < 8; ++g) s += redp[g*HID + tid];
    projo[(b*25 + cs)*HID + tid] = s;
  }
  if (tid == 0) logito[b*32 + cs] = red2[0] + red2[1] + ba[0];
}

// ---------------- K4: fused attention + MLP + packed scatter --------------------------
// grid (32 chunks, B) x 256 thr; 2 threads per position. Interior positions
// (all 24 neighbors case (mid,mid)) collapse to a per-batch constant pred.
__global__ __launch_bounds__(256) void k_pospack(
    const int* __restrict__ mask, const int* __restrict__ nbr_idx, const int* __restrict__ nbr_cnt,
    const int* __restrict__ /*unused*/, const float* __restrict__ logiti,
    const float* __restrict__ proji, const float* __restrict__ cbasei,
    const float* __restrict__ W2, const float* __restrict__ b2,
    float* __restrict__ out)
{
  const int b = blockIdx.y, chunk = blockIdx.x, tid = threadIdx.x;
  __shared__ float4 proj_s[25 * 32];
  __shared__ float4 cbase_s[32];
  __shared__ float  logit_s[32];
  __shared__ float  w2_s[2 * HID];
  __shared__ float  ippart[2][2];
  __shared__ int    bcnt_s[4];
  __shared__ int    wcnt_s[4];

  const float4* pj = (const float4*)(proji + b*25*HID);
  for (int i = tid; i < 25*32; i += 256) proj_s[i] = pj[i];
  if (tid < 32) cbase_s[tid] = ((const float4*)(cbasei + b*HID))[tid];
  if (tid < 32) logit_s[tid] = (tid < 25) ? logiti[b*32 + tid] : 0.f;
  w2_s[tid] = W2[tid];

  // scan base: # masked positions in [0, chunk*128)
  const int p0 = chunk * 128;
  {
    int cnt = 0;
    const int4* m4 = (const int4*)(mask + b*HWSZ);
    for (int i = tid; i < (p0 >> 2); i += 256) {
      const int4 v = m4[i];
      cnt += (v.x > 0) + (v.y > 0) + (v.z > 0) + (v.w > 0);
    }
    #pragma unroll
    for (int off = 1; off < 64; off <<= 1) cnt += __shfl_xor(cnt, off);
    if ((tid & 63) == 0) bcnt_s[tid >> 6] = cnt;
  }
  __syncthreads();

  // interior pred: gelu(proj[12] + cbase) @ W2 + b2 (per-batch constant)
  if (tid < HID) {
    const float g = gelu_f(((const float*)proj_s)[12*HID + tid] + ((const float*)cbase_s)[tid]);
    float q0 = g * w2_s[tid*2 + 0];
    float q1 = g * w2_s[tid*2 + 1];
    #pragma unroll
    for (int off = 1; off < 64; off <<= 1) {
      q0 += __shfl_xor(q0, off);
      q1 += __shfl_xor(q1, off);
    }
    if ((tid & 63) == 0) { ippart[tid >> 6][0] = q0; ippart[tid >> 6][1] = q1; }
  }
  __syncthreads();
  const int   base = bcnt_s[0] + bcnt_s[1] + bcnt_s[2] + bcnt_s[3];
  const float ip0 = ippart[0][0] + ippart[1][0] + b2[0];
  const float ip1 = ippart[0][1] + ippart[1][1] + b2[1];

  const int p = p0 + (tid >> 1);
  const int half = tid & 1;
  const bool pok = (p < HWSZ);
  const int pc = pok ? p : 0;
  const int r = pc / WWID, cc = pc % WWID;
  const bool interior = (r >= 4) && (r <= HH-5) && (cc >= 4) && (cc <= WWID-5);
  const bool mp = pok && (mask[b*HWSZ + pc] > 0);

  float pr0 = ip0, pr1 = ip1;
  if (pok && !interior) {
    const int cnt = nbr_cnt[pc];
    float ev[NMAX];
    int   cid[NMAX];
    #pragma unroll
    for (int n = 0; n < NMAX; ++n) {
      const int q = nbr_idx[pc*NMAX + n];
      const int qr = q / WWID, qc = q % WWID;
      const int r5 = (qr == 0) ? 0 : (qr == 1) ? 1 : (qr == HH-2) ? 3 : (qr == HH-1) ? 4 : 2;
      const int c5 = (qc == 0) ? 0 : (qc == 1) ? 1 : (qc == WWID-2) ? 3 : (qc == WWID-1) ? 4 : 2;
      const int cd = r5*5 + c5;
      cid[n] = cd;
      const bool ok = (n < cnt) && (mask[b*HWSZ + q] == 0);
      ev[n] = ok ? logit_s[cd] : -10000.0f;
    }
    float mx = ev[0];
    #pragma unroll
    for (int n = 1; n < NMAX; ++n) mx = fmaxf(mx, ev[n]);
    float s = 0.f;
    #pragma unroll
    for (int n = 0; n < NMAX; ++n) { ev[n] = expf(ev[n] - mx); s += ev[n]; }
    const float inv = 1.f / s;

    float a0 = 0.f, a1 = 0.f;
    const int hb = half * 16;
    #pragma unroll 4
    for (int hq = 0; hq < 16; ++hq) {
      float4 a = make_float4(0.f, 0.f, 0.f, 0.f);
      #pragma unroll
      for (int n = 0; n < NMAX; ++n) {
        const float4 pv = proj_s[cid[n]*32 + hb + hq];
        const float w = ev[n];
        a.x = fmaf(w, pv.x, a.x);
        a.y = fmaf(w, pv.y, a.y);
        a.z = fmaf(w, pv.z, a.z);
        a.w = fmaf(w, pv.w, a.w);
      }
      const float4 cb = cbase_s[hb + hq];
      const int h0 = (hb + hq) * 4;
      const float g0 = gelu_f(fmaf(inv, a.x, cb.x));
      const float g1v = gelu_f(fmaf(inv, a.y, cb.y));
      const float g2 = gelu_f(fmaf(inv, a.z, cb.z));
      const float g3 = gelu_f(fmaf(inv, a.w, cb.w));
      a0 = fmaf(g0, w2_s[(h0+0)*2+0], a0); a1 = fmaf(g0, w2_s[(h0+0)*2+1], a1);
      a0 = fmaf(g1v, w2_s[(h0+1)*2+0], a0); a1 = fmaf(g1v, w2_s[(h0+1)*2+1], a1);
      a0 = fmaf(g2, w2_s[(h0+2)*2+0], a0); a1 = fmaf(g2, w2_s[(h0+2)*2+1], a1);
      a0 = fmaf(g3, w2_s[(h0+3)*2+0], a0); a1 = fmaf(g3, w2_s[(h0+3)*2+1], a1);
    }
    a0 += __shfl_xor(a0, 1);
    a1 += __shfl_xor(a1, 1);
    pr0 = a0 + b2[0];
    pr1 = a1 + b2[1];
  }

  // in-block packing: ballot over (masked && half==0), order = position order
  const unsigned long long bal = __ballot(mp && half == 0);
  const int lane = tid & 63;
  const int myidx = __popcll(bal & ((1ull << lane) - 1ull));
  if (lane == 0) wcnt_s[tid >> 6] = (int)__popcll(bal);
  __syncthreads();
  int wbase = 0;
  for (int w = 0; w < (tid >> 6); ++w) wbase += wcnt_s[w];
  if (mp && half == 0) {
    const int slot = base + wbase + myidx;
    float* predo = out + b*HWSZ*2;
    float* idxo  = out + NB*HWSZ*2 + b*HWSZ*2;
    float* valo  = out + NB*HWSZ*4 + b*HWSZ;
    predo[slot*2 + 0] = pr0;
    predo[slot*2 + 1] = pr1;
    idxo[slot*2 + 0] = (float)r;
    idxo[slot*2 + 1] = (float)cc;
    valo[slot] = 1.0f;
  }
}

extern "C" void kernel_launch(void* const* d_in, const int* in_sizes, int n_in,
                              void* d_out, int out_size, void* d_ws, size_t ws_size,
                              hipStream_t stream) {
  (void)in_sizes; (void)n_in; (void)out_size; (void)ws_size;
  const float* latent  = (const float*)d_in[1];
  const int*   mask    = (const int*)d_in[2];
  const int*   nbr_idx = (const int*)d_in[3];
  const int*   nbr_cnt = (const int*)d_in[4];
  const float* Wl  = (const float*)d_in[5];
  const float* bl  = (const float*)d_in[6];
  const float* Wt  = (const float*)d_in[7];
  const float* bt  = (const float*)d_in[8];
  const float* g1p = (const float*)d_in[9];
  const float* b1g = (const float*)d_in[10];
  const float* Wc  = (const float*)d_in[11];
  const float* bc  = (const float*)d_in[12];
  const float* Wa  = (const float*)d_in[13];
  const float* ba  = (const float*)d_in[14];
  const float* W1  = (const float*)d_in[15];
  const float* b1p = (const float*)d_in[16];
  const float* W2  = (const float*)d_in[17];
  const float* b2  = (const float*)d_in[18];

  float* ws    = (float*)d_ws;
  float* u     = ws;               // 8*10*128 = 10240
  float* t2    = ws + 10240;       // 8*9*9*128 = 82944
  float* logit = ws + 93184;       // 8*32 = 256
  float* proj  = ws + 93440;       // 8*25*128 = 25600
  float* cbase = ws + 119040;      // 8*128 = 1024

  dim3 gA(10, NB);
  k_tap<<<gA, 256, 0, stream>>>(latent, Wl, bl, Wt, W1, b1p, u, cbase, (float*)d_out);
  dim3 gB(9, NB);
  k_pre2<<<gB, 256, 0, stream>>>(u, bt, g1p, b1g, Wc, t2);
  k_pre3<<<NB*25, 256, 0, stream>>>(t2, bc, Wa, ba, W1, logit, proj);
  dim3 gC(32, NB);
  k_pospack<<<gC, 256, 0, stream>>>(mask, nbr_idx, nbr_cnt, nullptr, logit, proj, cbase, W2, b2,
                                    (float*)d_out);
}

// Round 5
// 48.067 us; speedup vs baseline: 2.0148x; 1.1776x over previous
//
#include <hip/hip_runtime.h>
#include <cmath>

#define HH   93
#define WWID 44
#define HWSZ 4092
#define NMAX 24
#define HID  128
#define LATD 1024
#define NB   8

__device__ __forceinline__ float gelu_f(float x) {
  return 0.5f * x * (1.0f + erff(x * 0.70710678118654752440f));
}

// case3 of source row (r + kr - 1) as function of (case5 of r, kr); -1 = out of range
__device__ __constant__ int c_map[5][3] = {{-1,0,1},{0,1,1},{1,1,1},{1,1,2},{1,2,-1}};

// ---------------- K0: partial lat@Wl (16-way split) + zero d_out ----------------------
// grid (16 splits, B) x 256 thr; thread = (h4, ig); 8 float4 loads each.
__global__ __launch_bounds__(256) void k_lc_part(
    const float* __restrict__ latent, const float* __restrict__ Wl,
    float* __restrict__ part, float* __restrict__ outz)
{
  const int split = blockIdx.x, b = blockIdx.y, tid = threadIdx.x;
  const int h4 = tid & 31, ig = tid >> 5;

  // zero d_out: 163680 floats = 40920 float4 over 128*256 = 32768 threads
  {
    const int gtid = (b * 16 + split) * 256 + tid;
    float4* oz = (float4*)outz;
    const float4 z = make_float4(0.f, 0.f, 0.f, 0.f);
    for (int i = gtid; i < (NB*HWSZ*5)/4; i += 32768) oz[i] = z;
  }

  const int L0 = split * 64 + ig * 8;
  const float* lat = latent + b * LATD;
  const float4* w4 = (const float4*)Wl;
  float4 a = make_float4(0.f, 0.f, 0.f, 0.f);
  #pragma unroll
  for (int i = 0; i < 8; ++i) {
    const int L = L0 + i;
    const float lv = lat[L];
    const float4 wv = w4[L*32 + h4];
    a.x = fmaf(lv, wv.x, a.x); a.y = fmaf(lv, wv.y, a.y);
    a.z = fmaf(lv, wv.z, a.z); a.w = fmaf(lv, wv.w, a.w);
  }
  __shared__ float red[8 * HID];
  ((float4*)red)[ig*32 + h4] = a;
  __syncthreads();
  if (tid < HID) {
    float s = 0.f;
    #pragma unroll
    for (int g = 0; g < 8; ++g) s += red[g*HID + tid];
    part[(b*16 + split)*HID + tid] = s;
  }
}

// ---------------- K1: per-tap reduction u[b][tap][ch]; tap 9 -> cbase -----------------
// grid (10 taps, B) x 256 thr. lc finalized from 16 L2-hot partials.
__global__ __launch_bounds__(256) void k_tap(
    const float* __restrict__ part, const float* __restrict__ bl,
    const float* __restrict__ Wt, const float* __restrict__ W1, const float* __restrict__ b1p,
    float* __restrict__ u, float* __restrict__ cbo)
{
  const int tap = blockIdx.x, b = blockIdx.y, tid = threadIdx.x;
  const int h4 = tid & 31, ig = tid >> 5;
  __shared__ float lc_s[HID];
  __shared__ float red[8 * HID];
  if (tid < HID) {
    float s = bl[tid];
    #pragma unroll
    for (int sp = 0; sp < 16; ++sp) s += part[(b*16 + sp)*HID + tid];
    lc_s[tid] = gelu_f(s);
  }
  __syncthreads();
  const float4* w4 = (tap < 9) ? ((const float4*)(Wt + tap*HID*HID))
                               : ((const float4*)(W1 + HID*HID));
  float4 a = make_float4(0.f, 0.f, 0.f, 0.f);
  #pragma unroll
  for (int i = 0; i < 16; ++i) {
    const int I = ig*16 + i;
    const float lv = lc_s[I];
    const float4 wv = w4[I*32 + h4];
    a.x = fmaf(lv, wv.x, a.x); a.y = fmaf(lv, wv.y, a.y);
    a.z = fmaf(lv, wv.z, a.z); a.w = fmaf(lv, wv.w, a.w);
  }
  ((float4*)red)[ig*32 + h4] = a;
  __syncthreads();
  if (tid < HID) {
    float s = 0.f;
    #pragma unroll
    for (int g = 0; g < 8; ++g) s += red[g*HID + tid];
    if (tap < 9) u[(b*10 + tap)*HID + tid] = s;
    else         cbo[b*HID + tid] = b1p[tid] + s;
  }
}

// ---------------- K2: fused GN + t2[b][tap][combo9][o] ---------------------------------
__global__ __launch_bounds__(256) void k_pre2(
    const float* __restrict__ u, const float* __restrict__ bt,
    const float* __restrict__ g1p, const float* __restrict__ b1g,
    const float* __restrict__ Wc, float* __restrict__ t2o)
{
  const int tap = blockIdx.x, b = blockIdx.y, tid = threadIdx.x;
  const int o4 = tid & 31, ig = tid >> 5;
  __shared__ float f2s[9 * HID];
  __shared__ float red[8 * 9 * HID];
  if (tid < HID) {
    const int t = tid;
    float uv[9];
    #pragma unroll
    for (int k = 0; k < 9; ++k) uv[k] = u[(b*10 + k)*HID + t];
    float ur[3][3];
    #pragma unroll
    for (int kc = 0; kc < 3; ++kc) {
      ur[0][kc] = uv[3+kc] + uv[6+kc];
      ur[1][kc] = uv[0+kc] + uv[3+kc] + uv[6+kc];
      ur[2][kc] = uv[0+kc] + uv[3+kc];
    }
    const float btv = bt[t];
    float f1v[9];
    #pragma unroll
    for (int a = 0; a < 3; ++a) {
      f1v[a*3+0] = btv + ur[a][1] + ur[a][2];
      f1v[a*3+1] = btv + ur[a][0] + ur[a][1] + ur[a][2];
      f1v[a*3+2] = btv + ur[a][0] + ur[a][1];
    }
    const float wr[3] = {1.f, (float)(HH-2), 1.f};
    const float wc[3] = {1.f, (float)(WWID-2), 1.f};
    float s1 = 0.f, s2 = 0.f;
    #pragma unroll
    for (int a = 0; a < 3; ++a)
      #pragma unroll
      for (int c = 0; c < 3; ++c) {
        const float w = wr[a] * wc[c];
        const float v = f1v[a*3+c];
        s1 += w * v;
        s2 += w * v * v;
      }
    #pragma unroll
    for (int off = 1; off < 16; off <<= 1) {
      s1 += __shfl_xor(s1, off);
      s2 += __shfl_xor(s2, off);
    }
    const float invN = 1.f / (float)(16 * HWSZ);
    const float mean = s1 * invN;
    const float var  = s2 * invN - mean * mean;
    const float sc = rsqrtf(var + 1e-5f) * g1p[t];
    const float sh = b1g[t] - mean * sc;
    #pragma unroll
    for (int k = 0; k < 9; ++k)
      f2s[k*HID + t] = gelu_f(fmaf(f1v[k], sc, sh));
  }
  __syncthreads();
  const float4* w4 = (const float4*)(Wc + tap*HID*HID);
  float4 acc[9];
  #pragma unroll
  for (int k = 0; k < 9; ++k) acc[k] = make_float4(0.f, 0.f, 0.f, 0.f);
  #pragma unroll
  for (int i = 0; i < 16; ++i) {
    const int I = ig*16 + i;
    const float4 wv = w4[I*32 + o4];
    #pragma unroll
    for (int k = 0; k < 9; ++k) {
      const float f = f2s[k*HID + I];
      acc[k].x = fmaf(f, wv.x, acc[k].x);
      acc[k].y = fmaf(f, wv.y, acc[k].y);
      acc[k].z = fmaf(f, wv.z, acc[k].z);
      acc[k].w = fmaf(f, wv.w, acc[k].w);
    }
  }
  #pragma unroll
  for (int k = 0; k < 9; ++k)
    ((float4*)red)[(ig*9 + k)*32 + o4] = acc[k];
  __syncthreads();
  for (int j = tid; j < 9*HID; j += 256) {
    float s = 0.f;
    #pragma unroll
    for (int g = 0; g < 8; ++g) s += red[g*9*HID + j];
    t2o[(b*9 + tap)*9*HID + j] = s;
  }
}

// ---------------- K3: f3(25 cases) + logit_case + proj_case ---------------------------
__global__ __launch_bounds__(256) void k_pre3(
    const float* __restrict__ t2i, const float* __restrict__ bc,
    const float* __restrict__ Wa, const float* __restrict__ ba,
    const float* __restrict__ W1,
    float* __restrict__ logito, float* __restrict__ projo)
{
  const int bid = blockIdx.x, b = bid / 25, cs = bid % 25;
  const int r5 = cs / 5, c5 = cs % 5, tid = threadIdx.x;
  __shared__ float f3s[HID];
  __shared__ float red2[2];
  __shared__ float redp[8 * HID];
  if (tid < HID) {
    float acc = bc[tid];
    #pragma unroll
    for (int kr = 0; kr < 3; ++kr) {
      const int rm = c_map[r5][kr];
      if (rm < 0) continue;
      #pragma unroll
      for (int kc = 0; kc < 3; ++kc) {
        const int cm = c_map[c5][kc];
        if (cm < 0) continue;
        acc += t2i[((b*9 + kr*3 + kc)*9 + rm*3 + cm)*HID + tid];
      }
    }
    const float f3v = gelu_f(acc);
    f3s[tid] = f3v;
    float pl = f3v * Wa[tid];
    #pragma unroll
    for (int off = 1; off < 64; off <<= 1) pl += __shfl_xor(pl, off);
    if ((tid & 63) == 0) red2[tid >> 6] = pl;
  }
  __syncthreads();
  const int h4 = tid & 31, og = tid >> 5;
  const float4* w4 = (const float4*)W1;
  float4 a = make_float4(0.f, 0.f, 0.f, 0.f);
  #pragma unroll
  for (int i = 0; i < 16; ++i) {
    const int o = og*16 + i;
    const float f = f3s[o];
    const float4 wv = w4[o*32 + h4];
    a.x = fmaf(f, wv.x, a.x); a.y = fmaf(f, wv.y, a.y);
    a.z = fmaf(f, wv.z, a.z); a.w = fmaf(f, wv.w, a.w);
  }
  ((float4*)redp)[og*32 + h4] = a;
  __syncthreads();
  if (tid < HID) {
    float s = 0.f;
    #pragma unroll
    for (int g = 0; g < 8; ++g) s += redp[g*HID + tid];
    projo[(b*25 + cs)*HID + tid] = s;
  }
  if (tid == 0) logito[b*32 + cs] = red2[0] + red2[1] + ba[0];
}

// ---------------- K4: fused attention + MLP + packed scatter --------------------------
// grid (32 chunks, B) x 256 thr; 2 threads per position. Interior positions
// (all 24 neighbors case (mid,mid)) collapse to a per-batch constant pred.
__global__ __launch_bounds__(256) void k_pospack(
    const int* __restrict__ mask, const int* __restrict__ nbr_idx, const int* __restrict__ nbr_cnt,
    const float* __restrict__ logiti,
    const float* __restrict__ proji, const float* __restrict__ cbasei,
    const float* __restrict__ W2, const float* __restrict__ b2,
    float* __restrict__ out)
{
  const int b = blockIdx.y, chunk = blockIdx.x, tid = threadIdx.x;
  __shared__ float4 proj_s[25 * 32];
  __shared__ float4 cbase_s[32];
  __shared__ float  logit_s[32];
  __shared__ float  w2_s[2 * HID];
  __shared__ float  ippart[2][2];
  __shared__ int    bcnt_s[4];
  __shared__ int    wcnt_s[4];

  const float4* pj = (const float4*)(proji + b*25*HID);
  for (int i = tid; i < 25*32; i += 256) proj_s[i] = pj[i];
  if (tid < 32) cbase_s[tid] = ((const float4*)(cbasei + b*HID))[tid];
  if (tid < 32) logit_s[tid] = (tid < 25) ? logiti[b*32 + tid] : 0.f;
  w2_s[tid] = W2[tid];

  // scan base: # masked positions in [0, chunk*128)
  const int p0 = chunk * 128;
  {
    int cnt = 0;
    const int4* m4 = (const int4*)(mask + b*HWSZ);
    for (int i = tid; i < (p0 >> 2); i += 256) {
      const int4 v = m4[i];
      cnt += (v.x > 0) + (v.y > 0) + (v.z > 0) + (v.w > 0);
    }
    #pragma unroll
    for (int off = 1; off < 64; off <<= 1) cnt += __shfl_xor(cnt, off);
    if ((tid & 63) == 0) bcnt_s[tid >> 6] = cnt;
  }
  __syncthreads();

  // interior pred: gelu(proj[12] + cbase) @ W2 + b2 (per-batch constant)
  if (tid < HID) {
    const float g = gelu_f(((const float*)proj_s)[12*HID + tid] + ((const float*)cbase_s)[tid]);
    float q0 = g * w2_s[tid*2 + 0];
    float q1 = g * w2_s[tid*2 + 1];
    #pragma unroll
    for (int off = 1; off < 64; off <<= 1) {
      q0 += __shfl_xor(q0, off);
      q1 += __shfl_xor(q1, off);
    }
    if ((tid & 63) == 0) { ippart[tid >> 6][0] = q0; ippart[tid >> 6][1] = q1; }
  }
  __syncthreads();
  const int   base = bcnt_s[0] + bcnt_s[1] + bcnt_s[2] + bcnt_s[3];
  const float ip0 = ippart[0][0] + ippart[1][0] + b2[0];
  const float ip1 = ippart[0][1] + ippart[1][1] + b2[1];

  const int p = p0 + (tid >> 1);
  const int half = tid & 1;
  const bool pok = (p < HWSZ);
  const int pc = pok ? p : 0;
  const int r = pc / WWID, cc = pc % WWID;
  const bool interior = (r >= 4) && (r <= HH-5) && (cc >= 4) && (cc <= WWID-5);
  const bool mp = pok && (mask[b*HWSZ + pc] > 0);

  float pr0 = ip0, pr1 = ip1;
  if (pok && !interior) {
    const int cnt = nbr_cnt[pc];
    float ev[NMAX];
    int   cid[NMAX];
    #pragma unroll
    for (int n = 0; n < NMAX; ++n) {
      const int q = nbr_idx[pc*NMAX + n];
      const int qr = q / WWID, qc = q % WWID;
      const int r5 = (qr == 0) ? 0 : (qr == 1) ? 1 : (qr == HH-2) ? 3 : (qr == HH-1) ? 4 : 2;
      const int c5 = (qc == 0) ? 0 : (qc == 1) ? 1 : (qc == WWID-2) ? 3 : (qc == WWID-1) ? 4 : 2;
      const int cd = r5*5 + c5;
      cid[n] = cd;
      const bool ok = (n < cnt) && (mask[b*HWSZ + q] == 0);
      ev[n] = ok ? logit_s[cd] : -10000.0f;
    }
    float mx = ev[0];
    #pragma unroll
    for (int n = 1; n < NMAX; ++n) mx = fmaxf(mx, ev[n]);
    float s = 0.f;
    #pragma unroll
    for (int n = 0; n < NMAX; ++n) { ev[n] = expf(ev[n] - mx); s += ev[n]; }
    const float inv = 1.f / s;

    float a0 = 0.f, a1 = 0.f;
    const int hb = half * 16;
    #pragma unroll 4
    for (int hq = 0; hq < 16; ++hq) {
      float4 a = make_float4(0.f, 0.f, 0.f, 0.f);
      #pragma unroll
      for (int n = 0; n < NMAX; ++n) {
        const float4 pv = proj_s[cid[n]*32 + hb + hq];
        const float w = ev[n];
        a.x = fmaf(w, pv.x, a.x);
        a.y = fmaf(w, pv.y, a.y);
        a.z = fmaf(w, pv.z, a.z);
        a.w = fmaf(w, pv.w, a.w);
      }
      const float4 cb = cbase_s[hb + hq];
      const int h0 = (hb + hq) * 4;
      const float g0 = gelu_f(fmaf(inv, a.x, cb.x));
      const float g1v = gelu_f(fmaf(inv, a.y, cb.y));
      const float g2 = gelu_f(fmaf(inv, a.z, cb.z));
      const float g3 = gelu_f(fmaf(inv, a.w, cb.w));
      a0 = fmaf(g0, w2_s[(h0+0)*2+0], a0); a1 = fmaf(g0, w2_s[(h0+0)*2+1], a1);
      a0 = fmaf(g1v, w2_s[(h0+1)*2+0], a0); a1 = fmaf(g1v, w2_s[(h0+1)*2+1], a1);
      a0 = fmaf(g2, w2_s[(h0+2)*2+0], a0); a1 = fmaf(g2, w2_s[(h0+2)*2+1], a1);
      a0 = fmaf(g3, w2_s[(h0+3)*2+0], a0); a1 = fmaf(g3, w2_s[(h0+3)*2+1], a1);
    }
    a0 += __shfl_xor(a0, 1);
    a1 += __shfl_xor(a1, 1);
    pr0 = a0 + b2[0];
    pr1 = a1 + b2[1];
  }

  // in-block packing: ballot over (masked && half==0), order = position order
  const unsigned long long bal = __ballot(mp && half == 0);
  const int lane = tid & 63;
  const int myidx = __popcll(bal & ((1ull << lane) - 1ull));
  if (lane == 0) wcnt_s[tid >> 6] = (int)__popcll(bal);
  __syncthreads();
  int wbase = 0;
  for (int w = 0; w < (tid >> 6); ++w) wbase += wcnt_s[w];
  if (mp && half == 0) {
    const int slot = base + wbase + myidx;
    float* predo = out + b*HWSZ*2;
    float* idxo  = out + NB*HWSZ*2 + b*HWSZ*2;
    float* valo  = out + NB*HWSZ*4 + b*HWSZ;
    predo[slot*2 + 0] = pr0;
    predo[slot*2 + 1] = pr1;
    idxo[slot*2 + 0] = (float)r;
    idxo[slot*2 + 1] = (float)cc;
    valo[slot] = 1.0f;
  }
}

extern "C" void kernel_launch(void* const* d_in, const int* in_sizes, int n_in,
                              void* d_out, int out_size, void* d_ws, size_t ws_size,
                              hipStream_t stream) {
  (void)in_sizes; (void)n_in; (void)out_size; (void)ws_size;
  const float* latent  = (const float*)d_in[1];
  const int*   mask    = (const int*)d_in[2];
  const int*   nbr_idx = (const int*)d_in[3];
  const int*   nbr_cnt = (const int*)d_in[4];
  const float* Wl  = (const float*)d_in[5];
  const float* bl  = (const float*)d_in[6];
  const float* Wt  = (const float*)d_in[7];
  const float* bt  = (const float*)d_in[8];
  const float* g1p = (const float*)d_in[9];
  const float* b1g = (const float*)d_in[10];
  const float* Wc  = (const float*)d_in[11];
  const float* bc  = (const float*)d_in[12];
  const float* Wa  = (const float*)d_in[13];
  const float* ba  = (const float*)d_in[14];
  const float* W1  = (const float*)d_in[15];
  const float* b1p = (const float*)d_in[16];
  const float* W2  = (const float*)d_in[17];
  const float* b2  = (const float*)d_in[18];

  float* ws    = (float*)d_ws;
  float* u     = ws;               // 8*10*128 = 10240
  float* t2    = ws + 10240;       // 8*9*9*128 = 82944
  float* logit = ws + 93184;       // 8*32 = 256
  float* proj  = ws + 93440;       // 8*25*128 = 25600
  float* cbase = ws + 119040;      // 8*128 = 1024
  float* part  = ws + 120064;      // 8*16*128 = 16384

  dim3 g0(16, NB);
  k_lc_part<<<g0, 256, 0, stream>>>(latent, Wl, part, (float*)d_out);
  dim3 gA(10, NB);
  k_tap<<<gA, 256, 0, stream>>>(part, bl, Wt, W1, b1p, u, cbase);
  dim3 gB(9, NB);
  k_pre2<<<gB, 256, 0, stream>>>(u, bt, g1p, b1g, Wc, t2);
  k_pre3<<<NB*25, 256, 0, stream>>>(t2, bc, Wa, ba, W1, logit, proj);
  dim3 gC(32, NB);
  k_pospack<<<gC, 256, 0, stream>>>(mask, nbr_idx, nbr_cnt, logit, proj, cbase, W2, b2,
                                    (float*)d_out);
}

// Round 6
// 47.070 us; speedup vs baseline: 2.0575x; 1.0212x over previous
//
#include <hip/hip_runtime.h>
#include <cmath>

#define HH   93
#define WWID 44
#define HWSZ 4092
#define NMAX 24
#define HID  128
#define LATD 1024
#define NB   8

__device__ __forceinline__ float gelu_f(float x) {
  return 0.5f * x * (1.0f + erff(x * 0.70710678118654752440f));
}

// case3 of source row (r + kr - 1) as function of (case5 of r, kr); -1 = out of range
__device__ __constant__ int c_map[5][3] = {{-1,0,1},{0,1,1},{1,1,1},{1,1,2},{1,2,-1}};

// ---------------- K1: redundant lc + per-tap reduction; tap 9 -> cbase; zero d_out ----
// grid (10 taps, B) x 1024 thr. Each block computes lc itself (Wl L2-resident across
// the 10 blocks per batch): 32 float4 loads/thread, batched 8-deep for ILP.
__global__ __launch_bounds__(1024) void k_tap10(
    const float* __restrict__ latent, const float* __restrict__ Wl,
    const float* __restrict__ bl,
    const float* __restrict__ Wt, const float* __restrict__ W1, const float* __restrict__ b1p,
    float* __restrict__ u, float* __restrict__ cbo, float* __restrict__ outz)
{
  const int tap = blockIdx.x, b = blockIdx.y, tid = threadIdx.x;
  const int h4 = tid & 31, ig = tid >> 5;   // ig in 0..31
  __shared__ float red[32 * HID];           // 16 KB
  __shared__ float lc_s[HID];

  // zero d_out: 40920 float4 over 80*1024 = 81920 threads
  {
    const int gtid = (b * 10 + tap) * 1024 + tid;
    float4* oz = (float4*)outz;
    if (gtid < (NB*HWSZ*5)/4) oz[gtid] = make_float4(0.f, 0.f, 0.f, 0.f);
  }

  // ---- lc partial: rows L = ig*32 .. ig*32+31, batched 8 for ILP ----
  {
    const float* lat = latent + b * LATD;
    const float4* w4 = (const float4*)Wl;
    float4 a = make_float4(0.f, 0.f, 0.f, 0.f);
    for (int i0 = 0; i0 < 32; i0 += 8) {
      float  lv[8];
      float4 wv[8];
      #pragma unroll
      for (int j = 0; j < 8; ++j) {
        const int L = ig*32 + i0 + j;
        lv[j] = lat[L];
        wv[j] = w4[L*32 + h4];
      }
      #pragma unroll
      for (int j = 0; j < 8; ++j) {
        a.x = fmaf(lv[j], wv[j].x, a.x);
        a.y = fmaf(lv[j], wv[j].y, a.y);
        a.z = fmaf(lv[j], wv[j].z, a.z);
        a.w = fmaf(lv[j], wv[j].w, a.w);
      }
    }
    ((float4*)red)[ig*32 + h4] = a;
  }
  __syncthreads();
  if (tid < HID) {
    float s = bl[tid];
    #pragma unroll 8
    for (int g = 0; g < 32; ++g) s += red[g*HID + tid];
    lc_s[tid] = gelu_f(s);
  }
  __syncthreads();

  // ---- tap reduction: u[tap] = lc @ Wt[tap]  (tap 9: lc @ W1[128:]) ----
  const float4* wt4 = (tap < 9) ? ((const float4*)(Wt + tap*HID*HID))
                                : ((const float4*)(W1 + HID*HID));
  float4 aa = make_float4(0.f, 0.f, 0.f, 0.f);
  #pragma unroll
  for (int j = 0; j < 4; ++j) {
    const int I = ig*4 + j;
    const float lv = lc_s[I];
    const float4 wv = wt4[I*32 + h4];
    aa.x = fmaf(lv, wv.x, aa.x); aa.y = fmaf(lv, wv.y, aa.y);
    aa.z = fmaf(lv, wv.z, aa.z); aa.w = fmaf(lv, wv.w, aa.w);
  }
  __syncthreads();
  ((float4*)red)[ig*32 + h4] = aa;
  __syncthreads();
  if (tid < HID) {
    float s = 0.f;
    #pragma unroll 8
    for (int g = 0; g < 32; ++g) s += red[g*HID + tid];
    if (tap < 9) u[(b*10 + tap)*HID + tid] = s;
    else         cbo[b*HID + tid] = b1p[tid] + s;
  }
}

// ---------------- K2: per-case GN + direct conv2 + logit + proj -----------------------
// grid (25 cases, B) x 256 thr. f2 recomputed from u per block (~100 ops);
// f3pre[o] = bc[o] + sum over valid (kr,kc) of f2[combo] . Wc[tap][.][o].
__global__ __launch_bounds__(256) void k_case(
    const float* __restrict__ u, const float* __restrict__ bt,
    const float* __restrict__ g1p, const float* __restrict__ b1g,
    const float* __restrict__ Wc, const float* __restrict__ bc,
    const float* __restrict__ Wa, const float* __restrict__ ba,
    const float* __restrict__ W1,
    float* __restrict__ logito, float* __restrict__ projo)
{
  const int cs = blockIdx.x, b = blockIdx.y;
  const int r5 = cs / 5, c5 = cs % 5;
  const int tid = threadIdx.x, o4 = tid & 31, ig = tid >> 5;
  __shared__ float f2s[9 * HID];
  __shared__ float red[8 * HID];
  __shared__ float f3s[HID];
  __shared__ float red2[2];

  // ---- GN -> f2 (9 cases) ----
  if (tid < HID) {
    const int t = tid;
    float uv[9];
    #pragma unroll
    for (int k = 0; k < 9; ++k) uv[k] = u[(b*10 + k)*HID + t];
    float ur[3][3];
    #pragma unroll
    for (int kc = 0; kc < 3; ++kc) {
      ur[0][kc] = uv[3+kc] + uv[6+kc];
      ur[1][kc] = uv[0+kc] + uv[3+kc] + uv[6+kc];
      ur[2][kc] = uv[0+kc] + uv[3+kc];
    }
    const float btv = bt[t];
    float f1v[9];
    #pragma unroll
    for (int a = 0; a < 3; ++a) {
      f1v[a*3+0] = btv + ur[a][1] + ur[a][2];
      f1v[a*3+1] = btv + ur[a][0] + ur[a][1] + ur[a][2];
      f1v[a*3+2] = btv + ur[a][0] + ur[a][1];
    }
    const float wr[3] = {1.f, (float)(HH-2), 1.f};
    const float wc[3] = {1.f, (float)(WWID-2), 1.f};
    float s1 = 0.f, s2 = 0.f;
    #pragma unroll
    for (int a = 0; a < 3; ++a)
      #pragma unroll
      for (int c = 0; c < 3; ++c) {
        const float w = wr[a] * wc[c];
        const float v = f1v[a*3+c];
        s1 += w * v;
        s2 += w * v * v;
      }
    #pragma unroll
    for (int off = 1; off < 16; off <<= 1) {
      s1 += __shfl_xor(s1, off);
      s2 += __shfl_xor(s2, off);
    }
    const float invN = 1.f / (float)(16 * HWSZ);
    const float mean = s1 * invN;
    const float var  = s2 * invN - mean * mean;
    const float sc = rsqrtf(var + 1e-5f) * g1p[t];
    const float sh = b1g[t] - mean * sc;
    #pragma unroll
    for (int k = 0; k < 9; ++k)
      f2s[k*HID + t] = gelu_f(fmaf(f1v[k], sc, sh));
  }
  __syncthreads();

  // ---- direct conv2 sum over valid taps ----
  float4 a = make_float4(0.f, 0.f, 0.f, 0.f);
  #pragma unroll
  for (int kr = 0; kr < 3; ++kr) {
    const int rm = c_map[r5][kr];
    if (rm < 0) continue;
    #pragma unroll
    for (int kc = 0; kc < 3; ++kc) {
      const int cm = c_map[c5][kc];
      if (cm < 0) continue;
      const float4* w4 = (const float4*)(Wc + (kr*3 + kc)*HID*HID);
      const float* f2p = &f2s[(rm*3 + cm)*HID];
      #pragma unroll
      for (int i = 0; i < 16; ++i) {
        const int I = ig*16 + i;
        const float f = f2p[I];
        const float4 wv = w4[I*32 + o4];
        a.x = fmaf(f, wv.x, a.x); a.y = fmaf(f, wv.y, a.y);
        a.z = fmaf(f, wv.z, a.z); a.w = fmaf(f, wv.w, a.w);
      }
    }
  }
  ((float4*)red)[ig*32 + o4] = a;
  __syncthreads();

  // ---- finalize f3, logit partials ----
  if (tid < HID) {
    float s = bc[tid];
    #pragma unroll
    for (int g = 0; g < 8; ++g) s += red[g*HID + tid];
    const float f3v = gelu_f(s);
    f3s[tid] = f3v;
    float pl = f3v * Wa[tid];
    #pragma unroll
    for (int off = 1; off < 64; off <<= 1) pl += __shfl_xor(pl, off);
    if ((tid & 63) == 0) red2[tid >> 6] = pl;
  }
  __syncthreads();

  // ---- proj = f3 @ W1[:128] ----
  const float4* w14 = (const float4*)W1;
  float4 aa = make_float4(0.f, 0.f, 0.f, 0.f);
  #pragma unroll
  for (int i = 0; i < 16; ++i) {
    const int I = ig*16 + i;
    const float f = f3s[I];
    const float4 wv = w14[I*32 + o4];
    aa.x = fmaf(f, wv.x, aa.x); aa.y = fmaf(f, wv.y, aa.y);
    aa.z = fmaf(f, wv.z, aa.z); aa.w = fmaf(f, wv.w, aa.w);
  }
  __syncthreads();
  ((float4*)red)[ig*32 + o4] = aa;
  __syncthreads();
  if (tid < HID) {
    float s = 0.f;
    #pragma unroll
    for (int g = 0; g < 8; ++g) s += red[g*HID + tid];
    projo[(b*25 + cs)*HID + tid] = s;
  }
  if (tid == 0) logito[b*32 + cs] = red2[0] + red2[1] + ba[0];
}

// ---------------- K3: fused attention + MLP + packed scatter --------------------------
// grid (32 chunks, B) x 256 thr; 2 threads per position. Interior positions
// (all 24 neighbors case (mid,mid)) collapse to a per-batch constant pred.
__global__ __launch_bounds__(256) void k_pospack(
    const int* __restrict__ mask, const int* __restrict__ nbr_idx, const int* __restrict__ nbr_cnt,
    const float* __restrict__ logiti,
    const float* __restrict__ proji, const float* __restrict__ cbasei,
    const float* __restrict__ W2, const float* __restrict__ b2,
    float* __restrict__ out)
{
  const int b = blockIdx.y, chunk = blockIdx.x, tid = threadIdx.x;
  __shared__ float4 proj_s[25 * 32];
  __shared__ float4 cbase_s[32];
  __shared__ float  logit_s[32];
  __shared__ float  w2_s[2 * HID];
  __shared__ float  ippart[2][2];
  __shared__ int    bcnt_s[4];
  __shared__ int    wcnt_s[4];

  const float4* pj = (const float4*)(proji + b*25*HID);
  for (int i = tid; i < 25*32; i += 256) proj_s[i] = pj[i];
  if (tid < 32) cbase_s[tid] = ((const float4*)(cbasei + b*HID))[tid];
  if (tid < 32) logit_s[tid] = (tid < 25) ? logiti[b*32 + tid] : 0.f;
  w2_s[tid] = W2[tid];

  // scan base: # masked positions in [0, chunk*128)
  const int p0 = chunk * 128;
  {
    int cnt = 0;
    const int4* m4 = (const int4*)(mask + b*HWSZ);
    for (int i = tid; i < (p0 >> 2); i += 256) {
      const int4 v = m4[i];
      cnt += (v.x > 0) + (v.y > 0) + (v.z > 0) + (v.w > 0);
    }
    #pragma unroll
    for (int off = 1; off < 64; off <<= 1) cnt += __shfl_xor(cnt, off);
    if ((tid & 63) == 0) bcnt_s[tid >> 6] = cnt;
  }
  __syncthreads();

  // interior pred: gelu(proj[12] + cbase) @ W2 + b2 (per-batch constant)
  if (tid < HID) {
    const float g = gelu_f(((const float*)proj_s)[12*HID + tid] + ((const float*)cbase_s)[tid]);
    float q0 = g * w2_s[tid*2 + 0];
    float q1 = g * w2_s[tid*2 + 1];
    #pragma unroll
    for (int off = 1; off < 64; off <<= 1) {
      q0 += __shfl_xor(q0, off);
      q1 += __shfl_xor(q1, off);
    }
    if ((tid & 63) == 0) { ippart[tid >> 6][0] = q0; ippart[tid >> 6][1] = q1; }
  }
  __syncthreads();
  const int   base = bcnt_s[0] + bcnt_s[1] + bcnt_s[2] + bcnt_s[3];
  const float ip0 = ippart[0][0] + ippart[1][0] + b2[0];
  const float ip1 = ippart[0][1] + ippart[1][1] + b2[1];

  const int p = p0 + (tid >> 1);
  const int half = tid & 1;
  const bool pok = (p < HWSZ);
  const int pc = pok ? p : 0;
  const int r = pc / WWID, cc = pc % WWID;
  const bool interior = (r >= 4) && (r <= HH-5) && (cc >= 4) && (cc <= WWID-5);
  const bool mp = pok && (mask[b*HWSZ + pc] > 0);

  float pr0 = ip0, pr1 = ip1;
  if (pok && !interior) {
    const int cnt = nbr_cnt[pc];
    float ev[NMAX];
    int   cid[NMAX];
    #pragma unroll
    for (int n = 0; n < NMAX; ++n) {
      const int q = nbr_idx[pc*NMAX + n];
      const int qr = q / WWID, qc = q % WWID;
      const int r5 = (qr == 0) ? 0 : (qr == 1) ? 1 : (qr == HH-2) ? 3 : (qr == HH-1) ? 4 : 2;
      const int c5 = (qc == 0) ? 0 : (qc == 1) ? 1 : (qc == WWID-2) ? 3 : (qc == WWID-1) ? 4 : 2;
      const int cd = r5*5 + c5;
      cid[n] = cd;
      const bool ok = (n < cnt) && (mask[b*HWSZ + q] == 0);
      ev[n] = ok ? logit_s[cd] : -10000.0f;
    }
    float mx = ev[0];
    #pragma unroll
    for (int n = 1; n < NMAX; ++n) mx = fmaxf(mx, ev[n]);
    float s = 0.f;
    #pragma unroll
    for (int n = 0; n < NMAX; ++n) { ev[n] = expf(ev[n] - mx); s += ev[n]; }
    const float inv = 1.f / s;

    float a0 = 0.f, a1 = 0.f;
    const int hb = half * 16;
    #pragma unroll 4
    for (int hq = 0; hq < 16; ++hq) {
      float4 a = make_float4(0.f, 0.f, 0.f, 0.f);
      #pragma unroll
      for (int n = 0; n < NMAX; ++n) {
        const float4 pv = proj_s[cid[n]*32 + hb + hq];
        const float w = ev[n];
        a.x = fmaf(w, pv.x, a.x);
        a.y = fmaf(w, pv.y, a.y);
        a.z = fmaf(w, pv.z, a.z);
        a.w = fmaf(w, pv.w, a.w);
      }
      const float4 cb = cbase_s[hb + hq];
      const int h0 = (hb + hq) * 4;
      const float g0 = gelu_f(fmaf(inv, a.x, cb.x));
      const float g1v = gelu_f(fmaf(inv, a.y, cb.y));
      const float g2 = gelu_f(fmaf(inv, a.z, cb.z));
      const float g3 = gelu_f(fmaf(inv, a.w, cb.w));
      a0 = fmaf(g0, w2_s[(h0+0)*2+0], a0); a1 = fmaf(g0, w2_s[(h0+0)*2+1], a1);
      a0 = fmaf(g1v, w2_s[(h0+1)*2+0], a0); a1 = fmaf(g1v, w2_s[(h0+1)*2+1], a1);
      a0 = fmaf(g2, w2_s[(h0+2)*2+0], a0); a1 = fmaf(g2, w2_s[(h0+2)*2+1], a1);
      a0 = fmaf(g3, w2_s[(h0+3)*2+0], a0); a1 = fmaf(g3, w2_s[(h0+3)*2+1], a1);
    }
    a0 += __shfl_xor(a0, 1);
    a1 += __shfl_xor(a1, 1);
    pr0 = a0 + b2[0];
    pr1 = a1 + b2[1];
  }

  // in-block packing: ballot over (masked && half==0), order = position order
  const unsigned long long bal = __ballot(mp && half == 0);
  const int lane = tid & 63;
  const int myidx = __popcll(bal & ((1ull << lane) - 1ull));
  if (lane == 0) wcnt_s[tid >> 6] = (int)__popcll(bal);
  __syncthreads();
  int wbase = 0;
  for (int w = 0; w < (tid >> 6); ++w) wbase += wcnt_s[w];
  if (mp && half == 0) {
    const int slot = base + wbase + myidx;
    float* predo = out + b*HWSZ*2;
    float* idxo  = out + NB*HWSZ*2 + b*HWSZ*2;
    float* valo  = out + NB*HWSZ*4 + b*HWSZ;
    predo[slot*2 + 0] = pr0;
    predo[slot*2 + 1] = pr1;
    idxo[slot*2 + 0] = (float)r;
    idxo[slot*2 + 1] = (float)cc;
    valo[slot] = 1.0f;
  }
}

extern "C" void kernel_launch(void* const* d_in, const int* in_sizes, int n_in,
                              void* d_out, int out_size, void* d_ws, size_t ws_size,
                              hipStream_t stream) {
  (void)in_sizes; (void)n_in; (void)out_size; (void)ws_size;
  const float* latent  = (const float*)d_in[1];
  const int*   mask    = (const int*)d_in[2];
  const int*   nbr_idx = (const int*)d_in[3];
  const int*   nbr_cnt = (const int*)d_in[4];
  const float* Wl  = (const float*)d_in[5];
  const float* bl  = (const float*)d_in[6];
  const float* Wt  = (const float*)d_in[7];
  const float* bt  = (const float*)d_in[8];
  const float* g1p = (const float*)d_in[9];
  const float* b1g = (const float*)d_in[10];
  const float* Wc  = (const float*)d_in[11];
  const float* bc  = (const float*)d_in[12];
  const float* Wa  = (const float*)d_in[13];
  const float* ba  = (const float*)d_in[14];
  const float* W1  = (const float*)d_in[15];
  const float* b1p = (const float*)d_in[16];
  const float* W2  = (const float*)d_in[17];
  const float* b2  = (const float*)d_in[18];

  float* ws    = (float*)d_ws;
  float* u     = ws;               // 8*10*128 = 10240
  float* logit = ws + 10240;       // 8*32 = 256
  float* proj  = ws + 10496;       // 8*25*128 = 25600
  float* cbase = ws + 36096;       // 8*128 = 1024

  dim3 gA(10, NB);
  k_tap10<<<gA, 1024, 0, stream>>>(latent, Wl, bl, Wt, W1, b1p, u, cbase, (float*)d_out);
  dim3 gB(25, NB);
  k_case<<<gB, 256, 0, stream>>>(u, bt, g1p, b1g, Wc, bc, Wa, ba, W1, logit, proj);
  dim3 gC(32, NB);
  k_pospack<<<gC, 256, 0, stream>>>(mask, nbr_idx, nbr_cnt, logit, proj, cbase, W2, b2,
                                    (float*)d_out);
}

// Round 7
// 45.298 us; speedup vs baseline: 2.1379x; 1.0391x over previous
//
#include <hip/hip_runtime.h>
#include <cmath>

#define HH   93
#define WWID 44
#define HWSZ 4092
#define NMAX 24
#define HID  128
#define LATD 1024
#define NB   8

__device__ __forceinline__ float gelu_f(float x) {
  return 0.5f * x * (1.0f + erff(x * 0.70710678118654752440f));
}

// case3 of source row (r + kr - 1) as function of (case5 of r, kr); -1 = out of range
__device__ __constant__ int c_map[5][3] = {{-1,0,1},{0,1,1},{1,1,1},{1,1,2},{1,2,-1}};

// ---------------- K1: redundant lc + per-tap reduction; tap 9 -> cbase; zero d_out ----
// grid (10 taps, B) x 1024 thr. Each block computes lc itself (Wl L2-resident across
// the 10 blocks per batch): 32 float4 loads/thread, batched 8-deep for ILP.
__global__ __launch_bounds__(1024) void k_tap10(
    const float* __restrict__ latent, const float* __restrict__ Wl,
    const float* __restrict__ bl,
    const float* __restrict__ Wt, const float* __restrict__ W1, const float* __restrict__ b1p,
    float* __restrict__ u, float* __restrict__ cbo, float* __restrict__ outz)
{
  const int tap = blockIdx.x, b = blockIdx.y, tid = threadIdx.x;
  const int h4 = tid & 31, ig = tid >> 5;   // ig in 0..31
  __shared__ float red[32 * HID];           // 16 KB
  __shared__ float lc_s[HID];

  // zero d_out: 40920 float4 over 80*1024 = 81920 threads
  {
    const int gtid = (b * 10 + tap) * 1024 + tid;
    float4* oz = (float4*)outz;
    if (gtid < (NB*HWSZ*5)/4) oz[gtid] = make_float4(0.f, 0.f, 0.f, 0.f);
  }

  // ---- lc partial: rows L = ig*32 .. ig*32+31, batched 8 for ILP ----
  {
    const float* lat = latent + b * LATD;
    const float4* w4 = (const float4*)Wl;
    float4 a = make_float4(0.f, 0.f, 0.f, 0.f);
    for (int i0 = 0; i0 < 32; i0 += 8) {
      float  lv[8];
      float4 wv[8];
      #pragma unroll
      for (int j = 0; j < 8; ++j) {
        const int L = ig*32 + i0 + j;
        lv[j] = lat[L];
        wv[j] = w4[L*32 + h4];
      }
      #pragma unroll
      for (int j = 0; j < 8; ++j) {
        a.x = fmaf(lv[j], wv[j].x, a.x);
        a.y = fmaf(lv[j], wv[j].y, a.y);
        a.z = fmaf(lv[j], wv[j].z, a.z);
        a.w = fmaf(lv[j], wv[j].w, a.w);
      }
    }
    ((float4*)red)[ig*32 + h4] = a;
  }
  __syncthreads();
  if (tid < HID) {
    float s = bl[tid];
    #pragma unroll 8
    for (int g = 0; g < 32; ++g) s += red[g*HID + tid];
    lc_s[tid] = gelu_f(s);
  }
  __syncthreads();

  // ---- tap reduction: u[tap] = lc @ Wt[tap]  (tap 9: lc @ W1[128:]) ----
  const float4* wt4 = (tap < 9) ? ((const float4*)(Wt + tap*HID*HID))
                                : ((const float4*)(W1 + HID*HID));
  float4 aa = make_float4(0.f, 0.f, 0.f, 0.f);
  #pragma unroll
  for (int j = 0; j < 4; ++j) {
    const int I = ig*4 + j;
    const float lv = lc_s[I];
    const float4 wv = wt4[I*32 + h4];
    aa.x = fmaf(lv, wv.x, aa.x); aa.y = fmaf(lv, wv.y, aa.y);
    aa.z = fmaf(lv, wv.z, aa.z); aa.w = fmaf(lv, wv.w, aa.w);
  }
  __syncthreads();
  ((float4*)red)[ig*32 + h4] = aa;
  __syncthreads();
  if (tid < HID) {
    float s = 0.f;
    #pragma unroll 8
    for (int g = 0; g < 32; ++g) s += red[g*HID + tid];
    if (tap < 9) u[(b*10 + tap)*HID + tid] = s;
    else         cbo[b*HID + tid] = b1p[tid] + s;
  }
}

// ---------------- K2: per-case GN + direct conv2 + logit + proj -----------------------
// grid (26 cases, B) x 256 thr. cs<25: case pipeline. cs==25: per-chunk mask scan bases.
__global__ __launch_bounds__(256) void k_case(
    const float* __restrict__ u, const float* __restrict__ bt,
    const float* __restrict__ g1p, const float* __restrict__ b1g,
    const float* __restrict__ Wc, const float* __restrict__ bc,
    const float* __restrict__ Wa, const float* __restrict__ ba,
    const float* __restrict__ W1, const int* __restrict__ mask,
    float* __restrict__ logito, float* __restrict__ projo, int* __restrict__ chunkbase)
{
  const int cs = blockIdx.x, b = blockIdx.y;
  const int tid = threadIdx.x;

  if (cs == 25) {
    // per-chunk (128 positions) masked-count + exclusive scan over 32 chunks
    if (tid < 32) {
      const int4* m4 = (const int4*)(mask + b*HWSZ);
      const int n4 = (tid == 31) ? 31 : 32;   // 4092 ints = 1023 int4; chunk 31 has 31
      int cnt = 0;
      for (int i = 0; i < n4; ++i) {
        const int4 v = m4[tid*32 + i];
        cnt += (v.x > 0) + (v.y > 0) + (v.z > 0) + (v.w > 0);
      }
      int s = cnt;
      #pragma unroll
      for (int off = 1; off < 32; off <<= 1) {
        const int t = __shfl_up(s, off);
        if (tid >= off) s += t;
      }
      chunkbase[b*32 + tid] = s - cnt;
    }
    return;
  }

  const int r5 = cs / 5, c5 = cs % 5;
  const int o4 = tid & 31, ig = tid >> 5;
  __shared__ float f2s[9 * HID];
  __shared__ float red[8 * HID];
  __shared__ float f3s[HID];
  __shared__ float red2[2];

  // ---- GN -> f2 (9 cases) ----
  if (tid < HID) {
    const int t = tid;
    float uv[9];
    #pragma unroll
    for (int k = 0; k < 9; ++k) uv[k] = u[(b*10 + k)*HID + t];
    float ur[3][3];
    #pragma unroll
    for (int kc = 0; kc < 3; ++kc) {
      ur[0][kc] = uv[3+kc] + uv[6+kc];
      ur[1][kc] = uv[0+kc] + uv[3+kc] + uv[6+kc];
      ur[2][kc] = uv[0+kc] + uv[3+kc];
    }
    const float btv = bt[t];
    float f1v[9];
    #pragma unroll
    for (int a = 0; a < 3; ++a) {
      f1v[a*3+0] = btv + ur[a][1] + ur[a][2];
      f1v[a*3+1] = btv + ur[a][0] + ur[a][1] + ur[a][2];
      f1v[a*3+2] = btv + ur[a][0] + ur[a][1];
    }
    const float wr[3] = {1.f, (float)(HH-2), 1.f};
    const float wc[3] = {1.f, (float)(WWID-2), 1.f};
    float s1 = 0.f, s2 = 0.f;
    #pragma unroll
    for (int a = 0; a < 3; ++a)
      #pragma unroll
      for (int c = 0; c < 3; ++c) {
        const float w = wr[a] * wc[c];
        const float v = f1v[a*3+c];
        s1 += w * v;
        s2 += w * v * v;
      }
    #pragma unroll
    for (int off = 1; off < 16; off <<= 1) {
      s1 += __shfl_xor(s1, off);
      s2 += __shfl_xor(s2, off);
    }
    const float invN = 1.f / (float)(16 * HWSZ);
    const float mean = s1 * invN;
    const float var  = s2 * invN - mean * mean;
    const float sc = rsqrtf(var + 1e-5f) * g1p[t];
    const float sh = b1g[t] - mean * sc;
    #pragma unroll
    for (int k = 0; k < 9; ++k)
      f2s[k*HID + t] = gelu_f(fmaf(f1v[k], sc, sh));
  }
  __syncthreads();

  // ---- direct conv2 sum over valid taps ----
  float4 a = make_float4(0.f, 0.f, 0.f, 0.f);
  #pragma unroll
  for (int kr = 0; kr < 3; ++kr) {
    const int rm = c_map[r5][kr];
    if (rm < 0) continue;
    #pragma unroll
    for (int kc = 0; kc < 3; ++kc) {
      const int cm = c_map[c5][kc];
      if (cm < 0) continue;
      const float4* w4 = (const float4*)(Wc + (kr*3 + kc)*HID*HID);
      const float* f2p = &f2s[(rm*3 + cm)*HID];
      #pragma unroll
      for (int i = 0; i < 16; ++i) {
        const int I = ig*16 + i;
        const float f = f2p[I];
        const float4 wv = w4[I*32 + o4];
        a.x = fmaf(f, wv.x, a.x); a.y = fmaf(f, wv.y, a.y);
        a.z = fmaf(f, wv.z, a.z); a.w = fmaf(f, wv.w, a.w);
      }
    }
  }
  ((float4*)red)[ig*32 + o4] = a;
  __syncthreads();

  // ---- finalize f3, logit partials ----
  if (tid < HID) {
    float s = bc[tid];
    #pragma unroll
    for (int g = 0; g < 8; ++g) s += red[g*HID + tid];
    const float f3v = gelu_f(s);
    f3s[tid] = f3v;
    float pl = f3v * Wa[tid];
    #pragma unroll
    for (int off = 1; off < 64; off <<= 1) pl += __shfl_xor(pl, off);
    if ((tid & 63) == 0) red2[tid >> 6] = pl;
  }
  __syncthreads();

  // ---- proj = f3 @ W1[:128] ----
  const float4* w14 = (const float4*)W1;
  float4 aa = make_float4(0.f, 0.f, 0.f, 0.f);
  #pragma unroll
  for (int i = 0; i < 16; ++i) {
    const int I = ig*16 + i;
    const float f = f3s[I];
    const float4 wv = w14[I*32 + o4];
    aa.x = fmaf(f, wv.x, aa.x); aa.y = fmaf(f, wv.y, aa.y);
    aa.z = fmaf(f, wv.z, aa.z); aa.w = fmaf(f, wv.w, aa.w);
  }
  __syncthreads();
  ((float4*)red)[ig*32 + o4] = aa;
  __syncthreads();
  if (tid < HID) {
    float s = 0.f;
    #pragma unroll
    for (int g = 0; g < 8; ++g) s += red[g*HID + tid];
    projo[(b*25 + cs)*HID + tid] = s;
  }
  if (tid == 0) logito[b*32 + cs] = red2[0] + red2[1] + ba[0];
}

// ---------------- K3: fused attention + MLP + packed scatter --------------------------
// grid (32 chunks, B) x 256 thr; 2 threads per position. Interior positions
// (all 24 neighbors case (mid,mid)) collapse to a per-batch constant pred.
// proj_s padded to stride 33 float4 to break the cid-stride bank conflict.
__global__ __launch_bounds__(256) void k_pospack(
    const int* __restrict__ mask, const int* __restrict__ nbr_idx, const int* __restrict__ nbr_cnt,
    const float* __restrict__ logiti,
    const float* __restrict__ proji, const float* __restrict__ cbasei,
    const float* __restrict__ W2, const float* __restrict__ b2,
    const int* __restrict__ chunkbase,
    float* __restrict__ out)
{
  const int b = blockIdx.y, chunk = blockIdx.x, tid = threadIdx.x;
  __shared__ float4 proj_s[25 * 33];
  __shared__ float4 cbase_s[32];
  __shared__ float  logit_s[32];
  __shared__ float  w2_s[2 * HID];
  __shared__ float  ippart[2][2];
  __shared__ int    wcnt_s[4];

  const float4* pj = (const float4*)(proji + b*25*HID);
  for (int i = tid; i < 25*32; i += 256) proj_s[(i >> 5)*33 + (i & 31)] = pj[i];
  if (tid < 32) cbase_s[tid] = ((const float4*)(cbasei + b*HID))[tid];
  if (tid < 32) logit_s[tid] = (tid < 25) ? logiti[b*32 + tid] : 0.f;
  w2_s[tid] = W2[tid];
  __syncthreads();

  // interior pred: gelu(proj[12] + cbase) @ W2 + b2 (per-batch constant)
  if (tid < HID) {
    const float g = gelu_f(((const float*)proj_s)[12*33*4 + tid] + ((const float*)cbase_s)[tid]);
    float q0 = g * w2_s[tid*2 + 0];
    float q1 = g * w2_s[tid*2 + 1];
    #pragma unroll
    for (int off = 1; off < 64; off <<= 1) {
      q0 += __shfl_xor(q0, off);
      q1 += __shfl_xor(q1, off);
    }
    if ((tid & 63) == 0) { ippart[tid >> 6][0] = q0; ippart[tid >> 6][1] = q1; }
  }
  __syncthreads();
  const int   base = chunkbase[b*32 + chunk];
  const float ip0 = ippart[0][0] + ippart[1][0] + b2[0];
  const float ip1 = ippart[0][1] + ippart[1][1] + b2[1];

  const int p0 = chunk * 128;
  const int p = p0 + (tid >> 1);
  const int half = tid & 1;
  const bool pok = (p < HWSZ);
  const int pc = pok ? p : 0;
  const int r = pc / WWID, cc = pc % WWID;
  const bool interior = (r >= 4) && (r <= HH-5) && (cc >= 4) && (cc <= WWID-5);
  const bool mp = pok && (mask[b*HWSZ + pc] > 0);

  float pr0 = ip0, pr1 = ip1;
  if (pok && !interior) {
    const int cnt = nbr_cnt[pc];
    float ev[NMAX];
    int   cid[NMAX];
    #pragma unroll
    for (int n = 0; n < NMAX; ++n) {
      const int q = nbr_idx[pc*NMAX + n];
      const int qr = q / WWID, qc = q % WWID;
      const int r5 = (qr == 0) ? 0 : (qr == 1) ? 1 : (qr == HH-2) ? 3 : (qr == HH-1) ? 4 : 2;
      const int c5 = (qc == 0) ? 0 : (qc == 1) ? 1 : (qc == WWID-2) ? 3 : (qc == WWID-1) ? 4 : 2;
      const int cd = r5*5 + c5;
      cid[n] = cd;
      const bool ok = (n < cnt) && (mask[b*HWSZ + q] == 0);
      ev[n] = ok ? logit_s[cd] : -10000.0f;
    }
    float mx = ev[0];
    #pragma unroll
    for (int n = 1; n < NMAX; ++n) mx = fmaxf(mx, ev[n]);
    float s = 0.f;
    #pragma unroll
    for (int n = 0; n < NMAX; ++n) { ev[n] = expf(ev[n] - mx); s += ev[n]; }
    const float inv = 1.f / s;

    float a0 = 0.f, a1 = 0.f;
    const int hb = half * 16;
    #pragma unroll 4
    for (int hq = 0; hq < 16; ++hq) {
      float4 a = make_float4(0.f, 0.f, 0.f, 0.f);
      #pragma unroll
      for (int n = 0; n < NMAX; ++n) {
        const float4 pv = proj_s[cid[n]*33 + hb + hq];
        const float w = ev[n];
        a.x = fmaf(w, pv.x, a.x);
        a.y = fmaf(w, pv.y, a.y);
        a.z = fmaf(w, pv.z, a.z);
        a.w = fmaf(w, pv.w, a.w);
      }
      const float4 cb = cbase_s[hb + hq];
      const int h0 = (hb + hq) * 4;
      const float g0 = gelu_f(fmaf(inv, a.x, cb.x));
      const float g1v = gelu_f(fmaf(inv, a.y, cb.y));
      const float g2 = gelu_f(fmaf(inv, a.z, cb.z));
      const float g3 = gelu_f(fmaf(inv, a.w, cb.w));
      a0 = fmaf(g0, w2_s[(h0+0)*2+0], a0); a1 = fmaf(g0, w2_s[(h0+0)*2+1], a1);
      a0 = fmaf(g1v, w2_s[(h0+1)*2+0], a0); a1 = fmaf(g1v, w2_s[(h0+1)*2+1], a1);
      a0 = fmaf(g2, w2_s[(h0+2)*2+0], a0); a1 = fmaf(g2, w2_s[(h0+2)*2+1], a1);
      a0 = fmaf(g3, w2_s[(h0+3)*2+0], a0); a1 = fmaf(g3, w2_s[(h0+3)*2+1], a1);
    }
    a0 += __shfl_xor(a0, 1);
    a1 += __shfl_xor(a1, 1);
    pr0 = a0 + b2[0];
    pr1 = a1 + b2[1];
  }

  // in-block packing: ballot over (masked && half==0), order = position order
  const unsigned long long bal = __ballot(mp && half == 0);
  const int lane = tid & 63;
  const int myidx = __popcll(bal & ((1ull << lane) - 1ull));
  if (lane == 0) wcnt_s[tid >> 6] = (int)__popcll(bal);
  __syncthreads();
  int wbase = 0;
  for (int w = 0; w < (tid >> 6); ++w) wbase += wcnt_s[w];
  if (mp && half == 0) {
    const int slot = base + wbase + myidx;
    float* predo = out + b*HWSZ*2;
    float* idxo  = out + NB*HWSZ*2 + b*HWSZ*2;
    float* valo  = out + NB*HWSZ*4 + b*HWSZ;
    predo[slot*2 + 0] = pr0;
    predo[slot*2 + 1] = pr1;
    idxo[slot*2 + 0] = (float)r;
    idxo[slot*2 + 1] = (float)cc;
    valo[slot] = 1.0f;
  }
}

extern "C" void kernel_launch(void* const* d_in, const int* in_sizes, int n_in,
                              void* d_out, int out_size, void* d_ws, size_t ws_size,
                              hipStream_t stream) {
  (void)in_sizes; (void)n_in; (void)out_size; (void)ws_size;
  const float* latent  = (const float*)d_in[1];
  const int*   mask    = (const int*)d_in[2];
  const int*   nbr_idx = (const int*)d_in[3];
  const int*   nbr_cnt = (const int*)d_in[4];
  const float* Wl  = (const float*)d_in[5];
  const float* bl  = (const float*)d_in[6];
  const float* Wt  = (const float*)d_in[7];
  const float* bt  = (const float*)d_in[8];
  const float* g1p = (const float*)d_in[9];
  const float* b1g = (const float*)d_in[10];
  const float* Wc  = (const float*)d_in[11];
  const float* bc  = (const float*)d_in[12];
  const float* Wa  = (const float*)d_in[13];
  const float* ba  = (const float*)d_in[14];
  const float* W1  = (const float*)d_in[15];
  const float* b1p = (const float*)d_in[16];
  const float* W2  = (const float*)d_in[17];
  const float* b2  = (const float*)d_in[18];

  float* ws    = (float*)d_ws;
  float* u     = ws;               // 8*10*128 = 10240
  float* logit = ws + 10240;       // 8*32 = 256
  float* proj  = ws + 10496;       // 8*25*128 = 25600
  float* cbase = ws + 36096;       // 8*128 = 1024
  int*   chunkbase = (int*)(ws + 37120);  // 8*32 ints

  dim3 gA(10, NB);
  k_tap10<<<gA, 1024, 0, stream>>>(latent, Wl, bl, Wt, W1, b1p, u, cbase, (float*)d_out);
  dim3 gB(26, NB);
  k_case<<<gB, 256, 0, stream>>>(u, bt, g1p, b1g, Wc, bc, Wa, ba, W1, mask,
                                 logit, proj, chunkbase);
  dim3 gC(32, NB);
  k_pospack<<<gC, 256, 0, stream>>>(mask, nbr_idx, nbr_cnt, logit, proj, cbase, W2, b2,
                                    chunkbase, (float*)d_out);
}